// Round 7
// baseline (381.712 us; speedup 1.0000x reference)
//
#include <hip/hip_runtime.h>

// AttentionXL: CUR=1024, FULL=2048, BS=4, D=1024, HN=16, HD=64, PREV=1024
// f16 MFMA 16x16x32 everywhere; fp32 accumulate/softmax.
// Scores pre-scaled: qfu = (q+b+u)*0.125; qv = qfu + (v-u)*0.125 in-register.

typedef _Float16 half8 __attribute__((ext_vector_type(8)));
typedef _Float16 half4v __attribute__((ext_vector_type(4)));
typedef float f32x4 __attribute__((ext_vector_type(4)));

typedef const __attribute__((address_space(1))) void* gas_ptr;
typedef __attribute__((address_space(3))) void* las_ptr;

__device__ __forceinline__ void load_lds16(const void* g, void* l) {
  __builtin_amdgcn_global_load_lds((gas_ptr)g, (las_ptr)l, 16, 0, 0);
}

// ---------------------------------------------------------------------------
// prep v10: activation fp32->f16 grid-strided (2048 blocks x 7 iters, uniform
// branch per iter) + weight convert+transpose (blocks [2048,3328)).
// ---------------------------------------------------------------------------
__global__ __launch_bounds__(256) void prep(
    const float* __restrict__ inputs, const float* __restrict__ full_inp,
    const float* __restrict__ pos_emb, const float* __restrict__ Wq,
    const float* __restrict__ Wkv, const float* __restrict__ Wpos,
    const float* __restrict__ Wproj, _Float16* __restrict__ o_in,
    _Float16* __restrict__ o_full, _Float16* __restrict__ o_pos,
    _Float16* __restrict__ owq, _Float16* __restrict__ owkv,
    _Float16* __restrict__ owpos, _Float16* __restrict__ owproj) {
  __shared__ _Float16 tile[64][65];
  const int bx = blockIdx.x;
  const int t = threadIdx.x;
  if (bx < 2048) {
#pragma unroll
    for (int it = 0; it < 7; ++it) {
      const size_t g = (size_t)bx * 256 + t + (size_t)it * (2048 * 256);
      float4 vv;
      _Float16* dptr;
      if (g < (1u << 20)) {  // inputs -> in_q_h, b-major
        const int rd = (int)(g >> 8), b = rd >> 10, i = rd & 1023;
        const size_t sg = ((size_t)(i * 4 + b) << 8) + (g & 255);
        vv = *(const float4*)(inputs + sg * 4);
        dptr = o_in + g * 4;
      } else if (g < (3u << 20)) {  // full_inp -> in_full_h, b-major
        const size_t gd = g - (1u << 20);
        const int rd = (int)(gd >> 8), b = rd >> 11, j = rd & 2047;
        const size_t sg = ((size_t)(j * 4 + b) << 8) + (gd & 255);
        vv = *(const float4*)(full_inp + sg * 4);
        dptr = o_full + gd * 4;
      } else {  // pos_emb plain
        const size_t gd = g - (3u << 20);
        vv = *(const float4*)(pos_emb + gd * 4);
        dptr = o_pos + gd * 4;
      }
      half4v hh;
      hh[0] = (_Float16)vv.x; hh[1] = (_Float16)vv.y;
      hh[2] = (_Float16)vv.z; hh[3] = (_Float16)vv.w;
      *(half4v*)dptr = hh;
    }
    return;
  }
  const int wb = bx - 2048;
  const float* W;
  _Float16* Wt;
  int N, tidx;
  if (wb < 256) { W = Wq; Wt = owq; N = 1024; tidx = wb; }
  else if (wb < 768) { W = Wkv; Wt = owkv; N = 2048; tidx = wb - 256; }
  else if (wb < 1024) { W = Wpos; Wt = owpos; N = 1024; tidx = wb - 768; }
  else { W = Wproj; Wt = owproj; N = 1024; tidx = wb - 1024; }
  const int K = 1024;
  const int n0 = (tidx % (N >> 6)) * 64, k0 = (tidx / (N >> 6)) * 64;
  const int rr = t >> 2, cc = (t & 3) * 16;
#pragma unroll
  for (int i = 0; i < 4; ++i) {
    float4 v = *(const float4*)&W[(size_t)(k0 + rr) * N + n0 + cc + i * 4];
    tile[rr][cc + i * 4 + 0] = (_Float16)v.x;
    tile[rr][cc + i * 4 + 1] = (_Float16)v.y;
    tile[rr][cc + i * 4 + 2] = (_Float16)v.z;
    tile[rr][cc + i * 4 + 3] = (_Float16)v.w;
  }
  __syncthreads();
  const int n = t >> 2, kc = (t & 3) * 16;
#pragma unroll
  for (int i = 0; i < 4; ++i) {
    half4v h;
    h[0] = tile[kc + i * 4 + 0][n];
    h[1] = tile[kc + i * 4 + 1][n];
    h[2] = tile[kc + i * 4 + 2][n];
    h[3] = tile[kc + i * 4 + 3][n];
    *(half4v*)&Wt[(size_t)(n0 + n) * K + k0 + kc + i * 4] = h;
  }
}

// ---------------------------------------------------------------------------
// Fused q/kv/r GEMM v10 (A matrices are b-major). 1408 blocks.
//  BK=64, XOR-swizzled staging + fragment reads.
// ---------------------------------------------------------------------------
__global__ __launch_bounds__(256, 2) void gemm3(
    const _Float16* __restrict__ Aq, const _Float16* __restrict__ Akv,
    const _Float16* __restrict__ Ar, const _Float16* __restrict__ Btq,
    const _Float16* __restrict__ Btkv, const _Float16* __restrict__ Btr,
    const float* __restrict__ bq, const float* __restrict__ bkv,
    const float* __restrict__ br, const float* __restrict__ uu,
    _Float16* __restrict__ qfu, _Float16* __restrict__ kf,
    _Float16* __restrict__ vfT, _Float16* __restrict__ rf) {
  __shared__ _Float16 smem[128 * 128];  // As=[0,8192), Bs=[8192,16384) halves
  _Float16* As = smem;
  _Float16* Bs = smem + 8192;
  const int gb = blockIdx.x;
  const _Float16* A;
  const _Float16* Bt;
  const float* bias;
  int mode, bm, bn;
  if (gb < 256) {
    mode = 1; A = Aq; Bt = Btq; bias = bq;
    bn = (gb & 7) * 128; bm = (gb >> 3) * 128;
  } else if (gb < 1280) {
    mode = 2; A = Akv; Bt = Btkv; bias = bkv;
    const int j = gb - 256;
    bn = (j & 15) * 128; bm = (j >> 4) * 128;
  } else {
    mode = 3; A = Ar; Bt = Btr; bias = br;
    const int j = gb - 1280;
    bn = (j & 7) * 128; bm = (j >> 3) * 128;
  }
  const int K = 1024;
  const int t = threadIdx.x, w = t >> 6, l = t & 63;
  const int l15 = l & 15, l4 = l >> 4;
  const int wm = (w >> 1) * 64, wn = (w & 1) * 64;

  f32x4 acc[4][4];
  const f32x4 z4 = {0.f, 0.f, 0.f, 0.f};
#pragma unroll
  for (int i = 0; i < 4; ++i)
#pragma unroll
    for (int j = 0; j < 4; ++j) acc[i][j] = z4;

  const char* Abase = (const char*)A + (size_t)bm * K * 2;
  const char* Bbase = (const char*)Bt + (size_t)bn * K * 2;

  for (int k0 = 0; k0 < K; k0 += 64) {
    __syncthreads();
#pragma unroll
    for (int iss = 0; iss < 4; ++iss) {
      const int off = w * 4096 + iss * 1024 + l * 16;
      const int row = off >> 7;
      const int sw = ((((off >> 4) & 7) ^ (row & 7)) << 4);
      load_lds16(Abase + (size_t)row * (K * 2) + k0 * 2 + sw, (char*)As + off);
      load_lds16(Bbase + (size_t)row * (K * 2) + k0 * 2 + sw, (char*)Bs + off);
    }
    __syncthreads();
#pragma unroll
    for (int ks = 0; ks < 2; ++ks) {
      const int ch = ((ks * 4 + l4) ^ (l15 & 7)) * 8;
      half8 af[4], bf[4];
#pragma unroll
      for (int mt = 0; mt < 4; ++mt)
        af[mt] = *(const half8*)&As[(wm + mt * 16 + l15) * 64 + ch];
#pragma unroll
      for (int nt = 0; nt < 4; ++nt)
        bf[nt] = *(const half8*)&Bs[(wn + nt * 16 + l15) * 64 + ch];
#pragma unroll
      for (int mt = 0; mt < 4; ++mt)
#pragma unroll
        for (int nt = 0; nt < 4; ++nt)
          acc[mt][nt] = __builtin_amdgcn_mfma_f32_16x16x32_f16(
              af[mt], bf[nt], acc[mt][nt], 0, 0, 0);
    }
  }

  if (mode == 2 && bn >= 1024) {
    // ---- V half: LDS transpose -> coalesced vfT[bh][d][j] stores ----
    const int b = bm >> 11, j0m = bm & 2047;
    const int hbase = (bn - 1024) >> 6;  // even
#pragma unroll
    for (int ch = 0; ch < 2; ++ch) {
      __syncthreads();
      if (((wn >> 6) & 1) == ch) {
#pragma unroll
        for (int mt = 0; mt < 4; ++mt)
#pragma unroll
          for (int r = 0; r < 4; ++r) {
            const int rowl = wm + mt * 16 + l4 * 4 + r;
#pragma unroll
            for (int nt = 0; nt < 4; ++nt) {
              const int coll = nt * 16 + l15;
              smem[rowl * 66 + coll] =
                  (_Float16)(acc[mt][nt][r] + bias[bn + wn + coll]);
            }
          }
      }
      __syncthreads();
#pragma unroll
      for (int it = 0; it < 4; ++it) {
        const int c = t + 256 * it;
        const int d = c >> 4, ck = c & 15;
        half8 v8;
#pragma unroll
        for (int z = 0; z < 8; ++z) v8[z] = smem[(ck * 8 + z) * 66 + d];
        *(half8*)&vfT[(((size_t)(b * 16 + hbase + ch) * 64 + d) << 11) + j0m +
                      ck * 8] = v8;
      }
    }
    return;
  }

#pragma unroll
  for (int mt = 0; mt < 4; ++mt)
#pragma unroll
    for (int r = 0; r < 4; ++r) {
      const int rowl = wm + mt * 16 + l4 * 4 + r;
#pragma unroll
      for (int nt = 0; nt < 4; ++nt) {
        const int col = bn + wn + nt * 16 + l15;
        const float val = acc[mt][nt][r] + bias[col];
        if (mode == 1) {
          const int b = bm >> 10, i0m = bm & 1023;
          const int h = col >> 6, d = col & 63;
          qfu[(((size_t)(b * 16 + h) * 1024 + i0m + rowl) << 6) + d] =
              (_Float16)((val + uu[col]) * 0.125f);
        } else if (mode == 2) {
          const int b = bm >> 11, j0m = bm & 2047;
          const int h = col >> 6, d = col & 63;
          kf[(((size_t)(b * 16 + h) * 2048 + j0m + rowl) << 6) + d] =
              (_Float16)val;
        } else {
          const int h = col >> 6, d = col & 63;
          rf[(((size_t)h * 2048 + bm + rowl) << 6) + d] = (_Float16)val;
        }
      }
    }
}

// ---------------------------------------------------------------------------
// proj GEMM v10: out f32 [M][N] = A @ Bt^T + bias. BK=64 + swizzle.
// ---------------------------------------------------------------------------
__global__ __launch_bounds__(256, 2) void gemm_proj(
    const _Float16* __restrict__ A, const _Float16* __restrict__ Bt,
    const float* __restrict__ bias, float* __restrict__ out0, int M, int N,
    int K) {
  __shared__ _Float16 As[128 * 64];
  __shared__ _Float16 Bs[128 * 64];
  const int t = threadIdx.x, w = t >> 6, l = t & 63;
  const int l15 = l & 15, l4 = l >> 4;
  const int bm = blockIdx.y * 128, bn = blockIdx.x * 128;
  const int wm = (w >> 1) * 64, wn = (w & 1) * 64;

  f32x4 acc[4][4];
  const f32x4 z4 = {0.f, 0.f, 0.f, 0.f};
#pragma unroll
  for (int i = 0; i < 4; ++i)
#pragma unroll
    for (int j = 0; j < 4; ++j) acc[i][j] = z4;

  const char* Abase = (const char*)A + (size_t)bm * K * 2;
  const char* Bbase = (const char*)Bt + (size_t)bn * K * 2;

  for (int k0 = 0; k0 < K; k0 += 64) {
    __syncthreads();
#pragma unroll
    for (int iss = 0; iss < 4; ++iss) {
      const int off = w * 4096 + iss * 1024 + l * 16;
      const int row = off >> 7;
      const int sw = ((((off >> 4) & 7) ^ (row & 7)) << 4);
      load_lds16(Abase + (size_t)row * (K * 2) + k0 * 2 + sw, (char*)As + off);
      load_lds16(Bbase + (size_t)row * (K * 2) + k0 * 2 + sw, (char*)Bs + off);
    }
    __syncthreads();
#pragma unroll
    for (int ks = 0; ks < 2; ++ks) {
      const int ch = ((ks * 4 + l4) ^ (l15 & 7)) * 8;
      half8 af[4], bf[4];
#pragma unroll
      for (int mt = 0; mt < 4; ++mt)
        af[mt] = *(const half8*)&As[(wm + mt * 16 + l15) * 64 + ch];
#pragma unroll
      for (int nt = 0; nt < 4; ++nt)
        bf[nt] = *(const half8*)&Bs[(wn + nt * 16 + l15) * 64 + ch];
#pragma unroll
      for (int mt = 0; mt < 4; ++mt)
#pragma unroll
        for (int nt = 0; nt < 4; ++nt)
          acc[mt][nt] = __builtin_amdgcn_mfma_f32_16x16x32_f16(
              af[mt], bf[nt], acc[mt][nt], 0, 0, 0);
    }
  }

#pragma unroll
  for (int mt = 0; mt < 4; ++mt)
#pragma unroll
    for (int r = 0; r < 4; ++r) {
      const int row = bm + wm + mt * 16 + l4 * 4 + r;
#pragma unroll
      for (int nt = 0; nt < 4; ++nt) {
        const int col = bn + wn + nt * 16 + l15;
        out0[(size_t)row * N + col] = acc[mt][nt][r] + bias[col];
      }
    }
}

// ---------------------------------------------------------------------------
// MFMA flash attention v11: no r-ring; r read directly from global/L2.
//  - rf slice is 2 heads x 256 KB per XCD (bh swizzle) -> L2-resident.
//  - LDS 32 KB (ks+vts+pA) -> up to 5 blocks/CU by LDS.
//  - content loop split per group so only one group's rb/sc/accP is live
//    (~150 VGPR natural, no launch-bounds cap -> no v6-style spill) ->
//    3 waves/SIMD = 3 blocks/CU (1.5x v9).
//  - load/use ordering: rb0 issued before content-g0 MFMAs; rb1 issued
//    before softmax-g0 (~400 cyc cover for ~200 cyc L2 latency).
//  - clamp m<=2047 identical to ring staging; masked lanes ignore values.
// ---------------------------------------------------------------------------
__global__ __launch_bounds__(256, 2) void attn_mfma(
    const _Float16* __restrict__ qfu,  // [bh][1024][64]  (q+b+u)*0.125
    const _Float16* __restrict__ kf,   // [bh][2048][64]
    const _Float16* __restrict__ vfT,  // [bh][64][2048]
    const _Float16* __restrict__ rf,   // [h][2048][64]
    const float* __restrict__ u,       // [16][64]
    const float* __restrict__ v,       // [16][64]
    _Float16* __restrict__ attn_out)   // [i*4+b][1024] f16
{
  __shared__ _Float16 ks[64 * 64];        // [j][d] swizzled
  __shared__ _Float16 vts[64 * 64];       // [d][j] swizzled
  __shared__ _Float16 pA[2][4][16 * 64];  // per-group, per-wave probs

  const int t = threadIdx.x, w = t >> 6, l = t & 63;
  const int l15 = l & 15, l4 = l >> 4;
  const int id = blockIdx.x;
  // XCD swizzle on id&63; qt in [0,8): first 256 ids heavy (bx 7..4),
  // second 256 light (bx 0..3) so (id, id+256) pairs sum njt = 50.
  const int bh = ((id >> 3) & 7) * 8 + (id & 7);
  const int qt = id >> 6;
  const int bx = (qt < 4) ? (7 - qt) : (qt - 4);
  const int i0 = bx * 128;
  const int h = bh & 15, b = bh >> 4;

  const char* kfb = (const char*)(kf + (((size_t)bh * 2048) << 6));
  const char* vg = (const char*)(vfT + (((size_t)bh) << 17));
  const _Float16* rg = rf + (((size_t)h) << 17);

  // q fragments for both groups; qv = qa + (v-u)*0.125 in-register
  half8 qa0[2], qa1[2], qv0[2], qv1[2];
  {
    half8 dl0, dl1;
#pragma unroll
    for (int z = 0; z < 8; ++z) {
      const int di = l4 * 8 + z;
      dl0[z] = (_Float16)(0.125f * (v[h * 64 + di] - u[h * 64 + di]));
      dl1[z] = (_Float16)(0.125f * (v[h * 64 + 32 + di] - u[h * 64 + 32 + di]));
    }
#pragma unroll
    for (int g = 0; g < 2; ++g) {
      const size_t qo =
          (((size_t)bh * 1024 + i0 + 64 * g + w * 16 + l15) << 6) + l4 * 8;
      qa0[g] = *(const half8*)(qfu + qo);
      qa1[g] = *(const half8*)(qfu + qo + 32);
      qv0[g] = qa0[g] + dl0;
      qv1[g] = qa1[g] + dl1;
    }
  }
  const f32x4 z4 = {0.f, 0.f, 0.f, 0.f};
  f32x4 o[2][4];
  float lsum[2][4];
#pragma unroll
  for (int g = 0; g < 2; ++g)
#pragma unroll
    for (int nt = 0; nt < 4; ++nt) { o[g][nt] = z4; lsum[g][nt] = 0.f; }

  const int njt = 2 * bx + 18;

  for (int jt = 0; jt < njt; ++jt) {
    const int j0 = jt * 64;
    const int m_base = j0 - i0 + 960;  // group0 base; group1 = m_base - 64
    __syncthreads();  // prior tile's reads done before overwrite
    // ---- stage K, V^T (swizzled source) ----
    {
      const char* kg = kfb + (size_t)j0 * 128;
#pragma unroll
      for (int iss = 0; iss < 2; ++iss) {
        const int off = w * 1024 + iss * 4096 + l * 16;
        const int row = off >> 7;
        const int cph = (off >> 4) & 7;
        const int sw = ((cph ^ (row & 7)) << 4);
        load_lds16(kg + (size_t)row * 128 + sw, (char*)ks + off);
        load_lds16(vg + (size_t)row * 4096 + (size_t)j0 * 2 + sw,
                   (char*)vts + off);
      }
    }
    __syncthreads();

    const int cw0 = i0 - j0 + 1024 + 16 * w;  // group0 mask horizon
    const bool act0 = cw0 >= -15;

    // ---- issue group0 position loads (direct from L2) ----
    half8 rb0[5][2];
#pragma unroll
    for (int p = 0; p < 5; ++p) {
      int m = m_base + (3 - w + p) * 16 + l15;
      m = m < 2047 ? m : 2047;
      const half8* rrow = (const half8*)(rg + ((size_t)m << 6));
      rb0[p][0] = rrow[l4];
      rb0[p][1] = rrow[4 + l4];
    }

    // ---- content scores group0 (hides rb0 latency) ----
    f32x4 sc[4];
#pragma unroll
    for (int nt = 0; nt < 4; ++nt) {
      const int row = nt * 16 + l15;
      const int rsw = row & 7;
      const half8 b0 = *(const half8*)&ks[row * 64 + ((l4 ^ rsw) * 8)];
      const half8 b1 = *(const half8*)&ks[row * 64 + (((4 + l4) ^ rsw) * 8)];
      f32x4 cc = z4;
      cc = __builtin_amdgcn_mfma_f32_16x16x32_f16(qa0[0], b0, cc, 0, 0, 0);
      cc = __builtin_amdgcn_mfma_f32_16x16x32_f16(qa1[0], b1, cc, 0, 0, 0);
      sc[nt] = cc;
    }
    // ---- position scores group0 ----
    f32x4 accP[5];
#pragma unroll
    for (int p = 0; p < 5; ++p) {
      f32x4 cc = z4;
      cc = __builtin_amdgcn_mfma_f32_16x16x32_f16(qv0[0], rb0[p][0], cc, 0, 0, 0);
      cc = __builtin_amdgcn_mfma_f32_16x16x32_f16(qv1[0], rb0[p][1], cc, 0, 0, 0);
      accP[p] = cc;
    }
    // ---- issue group1 position loads (hidden under softmax g0) ----
    half8 rb1[5][2];
#pragma unroll
    for (int p = 0; p < 5; ++p) {
      int m = m_base - 64 + (3 - w + p) * 16 + l15;
      m = m < 2047 ? m : 2047;
      const half8* rrow = (const half8*)(rg + ((size_t)m << 6));
      rb1[p][0] = rrow[l4];
      rb1[p][1] = rrow[4 + l4];
    }
    // ---- softmax group0 ----
    if (act0) {
      const int cw = cw0;
      if (cw >= 63) {
#pragma unroll
        for (int r = 0; r < 4; ++r) {
          const int thr = 4 * l4 + r;
          const int srcl = (l4 << 4) | ((15 + l15 - thr) & 15);
          float rot[5];
#pragma unroll
          for (int p = 0; p < 5; ++p) rot[p] = __shfl(accP[p][r], srcl, 64);
          float esum = 0.f;
          const int sw2 = (thr & 7) * 8;
#pragma unroll
          for (int nt = 0; nt < 4; ++nt) {
            const float pv = (l15 <= thr) ? rot[nt] : rot[nt + 1];
            const float e = __expf(sc[nt][r] + pv);
            esum += e;
            pA[0][w][thr * 64 + ((16 * nt + l15) ^ sw2)] = (_Float16)e;
          }
          lsum[0][r] += esum;
        }
      } else {
#pragma unroll
        for (int r = 0; r < 4; ++r) {
          const int thr = 4 * l4 + r;
          const int srcl = (l4 << 4) | ((15 + l15 - thr) & 15);
          float rot[5];
#pragma unroll
          for (int p = 0; p < 5; ++p) rot[p] = __shfl(accP[p][r], srcl, 64);
          float esum = 0.f;
          const int sw2 = (thr & 7) * 8;
#pragma unroll
          for (int nt = 0; nt < 4; ++nt) {
            const float pv = (l15 <= thr) ? rot[nt] : rot[nt + 1];
            const bool masked = (16 * nt + l15) > (cw + thr);
            const float e = masked ? 0.f : __expf(sc[nt][r] + pv);
            esum += e;
            pA[0][w][thr * 64 + ((16 * nt + l15) ^ sw2)] = (_Float16)e;
          }
          lsum[0][r] += esum;
        }
      }
    }
    // ---- content scores group1 ----
#pragma unroll
    for (int nt = 0; nt < 4; ++nt) {
      const int row = nt * 16 + l15;
      const int rsw = row & 7;
      const half8 b0 = *(const half8*)&ks[row * 64 + ((l4 ^ rsw) * 8)];
      const half8 b1 = *(const half8*)&ks[row * 64 + (((4 + l4) ^ rsw) * 8)];
      f32x4 cc = z4;
      cc = __builtin_amdgcn_mfma_f32_16x16x32_f16(qa0[1], b0, cc, 0, 0, 0);
      cc = __builtin_amdgcn_mfma_f32_16x16x32_f16(qa1[1], b1, cc, 0, 0, 0);
      sc[nt] = cc;
    }
    // ---- position scores group1 ----
#pragma unroll
    for (int p = 0; p < 5; ++p) {
      f32x4 cc = z4;
      cc = __builtin_amdgcn_mfma_f32_16x16x32_f16(qv0[1], rb1[p][0], cc, 0, 0, 0);
      cc = __builtin_amdgcn_mfma_f32_16x16x32_f16(qv1[1], rb1[p][1], cc, 0, 0, 0);
      accP[p] = cc;
    }
    // ---- softmax group1 (always active) ----
    {
      const int cw = cw0 + 64;
      if (cw >= 63) {
#pragma unroll
        for (int r = 0; r < 4; ++r) {
          const int thr = 4 * l4 + r;
          const int srcl = (l4 << 4) | ((15 + l15 - thr) & 15);
          float rot[5];
#pragma unroll
          for (int p = 0; p < 5; ++p) rot[p] = __shfl(accP[p][r], srcl, 64);
          float esum = 0.f;
          const int sw2 = (thr & 7) * 8;
#pragma unroll
          for (int nt = 0; nt < 4; ++nt) {
            const float pv = (l15 <= thr) ? rot[nt] : rot[nt + 1];
            const float e = __expf(sc[nt][r] + pv);
            esum += e;
            pA[1][w][thr * 64 + ((16 * nt + l15) ^ sw2)] = (_Float16)e;
          }
          lsum[1][r] += esum;
        }
      } else {
#pragma unroll
        for (int r = 0; r < 4; ++r) {
          const int thr = 4 * l4 + r;
          const int srcl = (l4 << 4) | ((15 + l15 - thr) & 15);
          float rot[5];
#pragma unroll
          for (int p = 0; p < 5; ++p) rot[p] = __shfl(accP[p][r], srcl, 64);
          float esum = 0.f;
          const int sw2 = (thr & 7) * 8;
#pragma unroll
          for (int nt = 0; nt < 4; ++nt) {
            const float pv = (l15 <= thr) ? rot[nt] : rot[nt + 1];
            const bool masked = (16 * nt + l15) > (cw + thr);
            const float e = masked ? 0.f : __expf(sc[nt][r] + pv);
            esum += e;
            pA[1][w][thr * 64 + ((16 * nt + l15) ^ sw2)] = (_Float16)e;
          }
          lsum[1][r] += esum;
        }
      }
    }

    // ---- PV: shared vts reads feed both groups ----
#pragma unroll
    for (int kk = 0; kk < 2; ++kk) {
      const int aoff = l15 * 64 + ((kk * 32 + l4 * 8) ^ ((l15 & 7) * 8));
      half8 a81 = *(const half8*)&pA[1][w][aoff];
      half8 a80;
      if (act0) a80 = *(const half8*)&pA[0][w][aoff];
#pragma unroll
      for (int nt = 0; nt < 4; ++nt) {
        const int row = nt * 16 + l15;
        const half8 b8 =
            *(const half8*)&vts[row * 64 + ((((kk << 2) + l4) ^ (row & 7)) * 8)];
        if (act0)
          o[0][nt] =
              __builtin_amdgcn_mfma_f32_16x16x32_f16(a80, b8, o[0][nt], 0, 0, 0);
        o[1][nt] =
            __builtin_amdgcn_mfma_f32_16x16x32_f16(a81, b8, o[1][nt], 0, 0, 0);
      }
    }
  }

  // ---- epilogue ----
#pragma unroll
  for (int g = 0; g < 2; ++g)
#pragma unroll
    for (int r = 0; r < 4; ++r) {
      float s = lsum[g][r];
      s += __shfl_xor(s, 1, 64);
      s += __shfl_xor(s, 2, 64);
      s += __shfl_xor(s, 4, 64);
      s += __shfl_xor(s, 8, 64);
      const float inv = 1.0f / s;
      const int i = i0 + 64 * g + w * 16 + l4 * 4 + r;
      const size_t base = ((size_t)i * 4 + b) * 1024 + h * 64;
#pragma unroll
      for (int nt = 0; nt < 4; ++nt)
        attn_out[base + nt * 16 + l15] = (_Float16)(o[g][nt][r] * inv);
    }
}

// ---------------------------------------------------------------------------
extern "C" void kernel_launch(void* const* d_in, const int* in_sizes, int n_in,
                              void* d_out, int out_size, void* d_ws,
                              size_t ws_size, hipStream_t stream) {
  const float* inputs   = (const float*)d_in[0];
  const float* pos_emb  = (const float*)d_in[1];
  const float* full_inp = (const float*)d_in[2];
  const float* u        = (const float*)d_in[3];
  const float* v        = (const float*)d_in[4];
  const float* W_kv   = (const float*)d_in[6];
  const float* b_kv   = (const float*)d_in[7];
  const float* W_q    = (const float*)d_in[8];
  const float* b_q    = (const float*)d_in[9];
  const float* W_pos  = (const float*)d_in[10];
  const float* b_pos  = (const float*)d_in[11];
  const float* W_proj = (const float*)d_in[12];
  const float* b_proj = (const float*)d_in[13];
  float* out = (float*)d_out;

  char* ws = (char*)d_ws;
  const size_t MB = 1024 * 1024;
  _Float16* in_q_h    = (_Float16*)(ws);            // 8 MB  (b-major 4096x1024)
  _Float16* in_full_h = (_Float16*)(ws + 8 * MB);   // 16 MB (b-major 8192x1024)
  _Float16* in_pos_h  = (_Float16*)(ws + 24 * MB);  // 4 MB  (2048x1024)
  _Float16* attn_h    = (_Float16*)(ws + 28 * MB);  // 8 MB  (4096x1024)
  _Float16* wq_t      = (_Float16*)(ws + 36 * MB);  // 2 MB
  _Float16* wkv_t     = (_Float16*)(ws + 38 * MB);  // 4 MB
  _Float16* wpos_t    = (_Float16*)(ws + 42 * MB);  // 2 MB
  _Float16* wproj_t   = (_Float16*)(ws + 44 * MB);  // 2 MB
  _Float16* qfu       = (_Float16*)(ws + 46 * MB);  // 8 MB  [bh][1024][64]
  _Float16* kf        = (_Float16*)(ws + 54 * MB);  // 16 MB [bh][2048][64]
  _Float16* vfT       = (_Float16*)(ws + 70 * MB);  // 16 MB [bh][64][2048]
  _Float16* rf        = (_Float16*)(ws + 86 * MB);  // 4 MB  [h][2048][64]

  const dim3 blk(256);
  prep<<<dim3(3328), blk, 0, stream>>>(inputs, full_inp, pos_emb, W_q, W_kv,
                                       W_pos, W_proj, in_q_h, in_full_h,
                                       in_pos_h, wq_t, wkv_t, wpos_t, wproj_t);
  gemm3<<<dim3(1408), blk, 0, stream>>>(in_q_h, in_full_h, in_pos_h, wq_t,
                                        wkv_t, wpos_t, b_q, b_kv, b_pos, u,
                                        qfu, kf, vfT, rf);
  attn_mfma<<<dim3(512), blk, 0, stream>>>(qfu, kf, vfT, rf, u, v, attn_h);
  gemm_proj<<<dim3(8, 32), blk, 0, stream>>>(attn_h, wproj_t, b_proj, out,
                                             4096, 1024, 1024);
}

// Round 8
// 336.156 us; speedup vs baseline: 1.1355x; 1.1355x over previous
//
#include <hip/hip_runtime.h>

// AttentionXL: CUR=1024, FULL=2048, BS=4, D=1024, HN=16, HD=64, PREV=1024
// f16 MFMA 16x16x32 everywhere; fp32 accumulate/softmax.
// Scores pre-scaled: qfu = (q+b+u)*0.125; qv = qfu + (v-u)*0.125 in-register.

typedef _Float16 half8 __attribute__((ext_vector_type(8)));
typedef _Float16 half4v __attribute__((ext_vector_type(4)));
typedef float f32x4 __attribute__((ext_vector_type(4)));

typedef const __attribute__((address_space(1))) void* gas_ptr;
typedef __attribute__((address_space(3))) void* las_ptr;

__device__ __forceinline__ void load_lds16(const void* g, void* l) {
  __builtin_amdgcn_global_load_lds((gas_ptr)g, (las_ptr)l, 16, 0, 0);
}

// ---------------------------------------------------------------------------
// prep v10: activation fp32->f16 grid-strided (2048 blocks x 7 iters, uniform
// branch per iter) + weight convert+transpose (blocks [2048,3328)).
// ---------------------------------------------------------------------------
__global__ __launch_bounds__(256) void prep(
    const float* __restrict__ inputs, const float* __restrict__ full_inp,
    const float* __restrict__ pos_emb, const float* __restrict__ Wq,
    const float* __restrict__ Wkv, const float* __restrict__ Wpos,
    const float* __restrict__ Wproj, _Float16* __restrict__ o_in,
    _Float16* __restrict__ o_full, _Float16* __restrict__ o_pos,
    _Float16* __restrict__ owq, _Float16* __restrict__ owkv,
    _Float16* __restrict__ owpos, _Float16* __restrict__ owproj) {
  __shared__ _Float16 tile[64][65];
  const int bx = blockIdx.x;
  const int t = threadIdx.x;
  if (bx < 2048) {
#pragma unroll
    for (int it = 0; it < 7; ++it) {
      const size_t g = (size_t)bx * 256 + t + (size_t)it * (2048 * 256);
      float4 vv;
      _Float16* dptr;
      if (g < (1u << 20)) {  // inputs -> in_q_h, b-major
        const int rd = (int)(g >> 8), b = rd >> 10, i = rd & 1023;
        const size_t sg = ((size_t)(i * 4 + b) << 8) + (g & 255);
        vv = *(const float4*)(inputs + sg * 4);
        dptr = o_in + g * 4;
      } else if (g < (3u << 20)) {  // full_inp -> in_full_h, b-major
        const size_t gd = g - (1u << 20);
        const int rd = (int)(gd >> 8), b = rd >> 11, j = rd & 2047;
        const size_t sg = ((size_t)(j * 4 + b) << 8) + (gd & 255);
        vv = *(const float4*)(full_inp + sg * 4);
        dptr = o_full + gd * 4;
      } else {  // pos_emb plain
        const size_t gd = g - (3u << 20);
        vv = *(const float4*)(pos_emb + gd * 4);
        dptr = o_pos + gd * 4;
      }
      half4v hh;
      hh[0] = (_Float16)vv.x; hh[1] = (_Float16)vv.y;
      hh[2] = (_Float16)vv.z; hh[3] = (_Float16)vv.w;
      *(half4v*)dptr = hh;
    }
    return;
  }
  const int wb = bx - 2048;
  const float* W;
  _Float16* Wt;
  int N, tidx;
  if (wb < 256) { W = Wq; Wt = owq; N = 1024; tidx = wb; }
  else if (wb < 768) { W = Wkv; Wt = owkv; N = 2048; tidx = wb - 256; }
  else if (wb < 1024) { W = Wpos; Wt = owpos; N = 1024; tidx = wb - 768; }
  else { W = Wproj; Wt = owproj; N = 1024; tidx = wb - 1024; }
  const int K = 1024;
  const int n0 = (tidx % (N >> 6)) * 64, k0 = (tidx / (N >> 6)) * 64;
  const int rr = t >> 2, cc = (t & 3) * 16;
#pragma unroll
  for (int i = 0; i < 4; ++i) {
    float4 v = *(const float4*)&W[(size_t)(k0 + rr) * N + n0 + cc + i * 4];
    tile[rr][cc + i * 4 + 0] = (_Float16)v.x;
    tile[rr][cc + i * 4 + 1] = (_Float16)v.y;
    tile[rr][cc + i * 4 + 2] = (_Float16)v.z;
    tile[rr][cc + i * 4 + 3] = (_Float16)v.w;
  }
  __syncthreads();
  const int n = t >> 2, kc = (t & 3) * 16;
#pragma unroll
  for (int i = 0; i < 4; ++i) {
    half4v h;
    h[0] = tile[kc + i * 4 + 0][n];
    h[1] = tile[kc + i * 4 + 1][n];
    h[2] = tile[kc + i * 4 + 2][n];
    h[3] = tile[kc + i * 4 + 3][n];
    *(half4v*)&Wt[(size_t)(n0 + n) * K + k0 + kc + i * 4] = h;
  }
}

// ---------------------------------------------------------------------------
// Fused q/kv/r GEMM v10 (A matrices are b-major). 1408 blocks.
//  BK=64, XOR-swizzled staging + fragment reads.
// ---------------------------------------------------------------------------
__global__ __launch_bounds__(256, 2) void gemm3(
    const _Float16* __restrict__ Aq, const _Float16* __restrict__ Akv,
    const _Float16* __restrict__ Ar, const _Float16* __restrict__ Btq,
    const _Float16* __restrict__ Btkv, const _Float16* __restrict__ Btr,
    const float* __restrict__ bq, const float* __restrict__ bkv,
    const float* __restrict__ br, const float* __restrict__ uu,
    _Float16* __restrict__ qfu, _Float16* __restrict__ kf,
    _Float16* __restrict__ vfT, _Float16* __restrict__ rf) {
  __shared__ _Float16 smem[128 * 128];  // As=[0,8192), Bs=[8192,16384) halves
  _Float16* As = smem;
  _Float16* Bs = smem + 8192;
  const int gb = blockIdx.x;
  const _Float16* A;
  const _Float16* Bt;
  const float* bias;
  int mode, bm, bn;
  if (gb < 256) {
    mode = 1; A = Aq; Bt = Btq; bias = bq;
    bn = (gb & 7) * 128; bm = (gb >> 3) * 128;
  } else if (gb < 1280) {
    mode = 2; A = Akv; Bt = Btkv; bias = bkv;
    const int j = gb - 256;
    bn = (j & 15) * 128; bm = (j >> 4) * 128;
  } else {
    mode = 3; A = Ar; Bt = Btr; bias = br;
    const int j = gb - 1280;
    bn = (j & 7) * 128; bm = (j >> 3) * 128;
  }
  const int K = 1024;
  const int t = threadIdx.x, w = t >> 6, l = t & 63;
  const int l15 = l & 15, l4 = l >> 4;
  const int wm = (w >> 1) * 64, wn = (w & 1) * 64;

  f32x4 acc[4][4];
  const f32x4 z4 = {0.f, 0.f, 0.f, 0.f};
#pragma unroll
  for (int i = 0; i < 4; ++i)
#pragma unroll
    for (int j = 0; j < 4; ++j) acc[i][j] = z4;

  const char* Abase = (const char*)A + (size_t)bm * K * 2;
  const char* Bbase = (const char*)Bt + (size_t)bn * K * 2;

  for (int k0 = 0; k0 < K; k0 += 64) {
    __syncthreads();
#pragma unroll
    for (int iss = 0; iss < 4; ++iss) {
      const int off = w * 4096 + iss * 1024 + l * 16;
      const int row = off >> 7;
      const int sw = ((((off >> 4) & 7) ^ (row & 7)) << 4);
      load_lds16(Abase + (size_t)row * (K * 2) + k0 * 2 + sw, (char*)As + off);
      load_lds16(Bbase + (size_t)row * (K * 2) + k0 * 2 + sw, (char*)Bs + off);
    }
    __syncthreads();
#pragma unroll
    for (int ks = 0; ks < 2; ++ks) {
      const int ch = ((ks * 4 + l4) ^ (l15 & 7)) * 8;
      half8 af[4], bf[4];
#pragma unroll
      for (int mt = 0; mt < 4; ++mt)
        af[mt] = *(const half8*)&As[(wm + mt * 16 + l15) * 64 + ch];
#pragma unroll
      for (int nt = 0; nt < 4; ++nt)
        bf[nt] = *(const half8*)&Bs[(wn + nt * 16 + l15) * 64 + ch];
#pragma unroll
      for (int mt = 0; mt < 4; ++mt)
#pragma unroll
        for (int nt = 0; nt < 4; ++nt)
          acc[mt][nt] = __builtin_amdgcn_mfma_f32_16x16x32_f16(
              af[mt], bf[nt], acc[mt][nt], 0, 0, 0);
    }
  }

  if (mode == 2 && bn >= 1024) {
    // ---- V half: LDS transpose -> coalesced vfT[bh][d][j] stores ----
    const int b = bm >> 11, j0m = bm & 2047;
    const int hbase = (bn - 1024) >> 6;  // even
#pragma unroll
    for (int ch = 0; ch < 2; ++ch) {
      __syncthreads();
      if (((wn >> 6) & 1) == ch) {
#pragma unroll
        for (int mt = 0; mt < 4; ++mt)
#pragma unroll
          for (int r = 0; r < 4; ++r) {
            const int rowl = wm + mt * 16 + l4 * 4 + r;
#pragma unroll
            for (int nt = 0; nt < 4; ++nt) {
              const int coll = nt * 16 + l15;
              smem[rowl * 66 + coll] =
                  (_Float16)(acc[mt][nt][r] + bias[bn + wn + coll]);
            }
          }
      }
      __syncthreads();
#pragma unroll
      for (int it = 0; it < 4; ++it) {
        const int c = t + 256 * it;
        const int d = c >> 4, ck = c & 15;
        half8 v8;
#pragma unroll
        for (int z = 0; z < 8; ++z) v8[z] = smem[(ck * 8 + z) * 66 + d];
        *(half8*)&vfT[(((size_t)(b * 16 + hbase + ch) * 64 + d) << 11) + j0m +
                      ck * 8] = v8;
      }
    }
    return;
  }

#pragma unroll
  for (int mt = 0; mt < 4; ++mt)
#pragma unroll
    for (int r = 0; r < 4; ++r) {
      const int rowl = wm + mt * 16 + l4 * 4 + r;
#pragma unroll
      for (int nt = 0; nt < 4; ++nt) {
        const int col = bn + wn + nt * 16 + l15;
        const float val = acc[mt][nt][r] + bias[col];
        if (mode == 1) {
          const int b = bm >> 10, i0m = bm & 1023;
          const int h = col >> 6, d = col & 63;
          qfu[(((size_t)(b * 16 + h) * 1024 + i0m + rowl) << 6) + d] =
              (_Float16)((val + uu[col]) * 0.125f);
        } else if (mode == 2) {
          const int b = bm >> 11, j0m = bm & 2047;
          const int h = col >> 6, d = col & 63;
          kf[(((size_t)(b * 16 + h) * 2048 + j0m + rowl) << 6) + d] =
              (_Float16)val;
        } else {
          const int h = col >> 6, d = col & 63;
          rf[(((size_t)h * 2048 + bm + rowl) << 6) + d] = (_Float16)val;
        }
      }
    }
}

// ---------------------------------------------------------------------------
// proj GEMM v12: out f32 [M][N] = A @ Bt^T + bias.
//  128x64 tiles -> 512 blocks -> 2 blocks/CU (was 256 blocks = 1 block/CU =
//  1 wave/SIMD, no latency hiding). acc[4][2]; BK=64 + swizzle as gemm3.
// ---------------------------------------------------------------------------
__global__ __launch_bounds__(256, 2) void gemm_proj(
    const _Float16* __restrict__ A, const _Float16* __restrict__ Bt,
    const float* __restrict__ bias, float* __restrict__ out0, int M, int N,
    int K) {
  __shared__ _Float16 As[128 * 64];
  __shared__ _Float16 Bs[64 * 64];
  const int t = threadIdx.x, w = t >> 6, l = t & 63;
  const int l15 = l & 15, l4 = l >> 4;
  const int bm = blockIdx.y * 128, bn = blockIdx.x * 64;
  const int wm = (w >> 1) * 64, wn = (w & 1) * 32;

  f32x4 acc[4][2];
  const f32x4 z4 = {0.f, 0.f, 0.f, 0.f};
#pragma unroll
  for (int i = 0; i < 4; ++i)
#pragma unroll
    for (int j = 0; j < 2; ++j) acc[i][j] = z4;

  const char* Abase = (const char*)A + (size_t)bm * K * 2;
  const char* Bbase = (const char*)Bt + (size_t)bn * K * 2;

  for (int k0 = 0; k0 < K; k0 += 64) {
    __syncthreads();
#pragma unroll
    for (int iss = 0; iss < 4; ++iss) {
      const int off = w * 4096 + iss * 1024 + l * 16;
      const int row = off >> 7;
      const int sw = ((((off >> 4) & 7) ^ (row & 7)) << 4);
      load_lds16(Abase + (size_t)row * (K * 2) + k0 * 2 + sw, (char*)As + off);
    }
#pragma unroll
    for (int iss = 0; iss < 2; ++iss) {
      const int off = w * 1024 + iss * 4096 + l * 16;
      const int row = off >> 7;
      const int sw = ((((off >> 4) & 7) ^ (row & 7)) << 4);
      load_lds16(Bbase + (size_t)row * (K * 2) + k0 * 2 + sw, (char*)Bs + off);
    }
    __syncthreads();
#pragma unroll
    for (int ks = 0; ks < 2; ++ks) {
      const int ch = ((ks * 4 + l4) ^ (l15 & 7)) * 8;
      half8 af[4], bf[2];
#pragma unroll
      for (int mt = 0; mt < 4; ++mt)
        af[mt] = *(const half8*)&As[(wm + mt * 16 + l15) * 64 + ch];
#pragma unroll
      for (int nt = 0; nt < 2; ++nt)
        bf[nt] = *(const half8*)&Bs[(wn + nt * 16 + l15) * 64 + ch];
#pragma unroll
      for (int mt = 0; mt < 4; ++mt)
#pragma unroll
        for (int nt = 0; nt < 2; ++nt)
          acc[mt][nt] = __builtin_amdgcn_mfma_f32_16x16x32_f16(
              af[mt], bf[nt], acc[mt][nt], 0, 0, 0);
    }
  }

#pragma unroll
  for (int mt = 0; mt < 4; ++mt)
#pragma unroll
    for (int r = 0; r < 4; ++r) {
      const int row = bm + wm + mt * 16 + l4 * 4 + r;
#pragma unroll
      for (int nt = 0; nt < 2; ++nt) {
        const int col = bn + wn + nt * 16 + l15;
        out0[(size_t)row * N + col] = acc[mt][nt][r] + bias[col];
      }
    }
}

// ---------------------------------------------------------------------------
// MFMA flash attention v12 = v9 (verified 101.9 us) + T5 s_setprio around
// MFMA clusters (m191: +4-7% attn when independent blocks share a CU).
// 128 q-rows per block (2 row-groups per wave); shared ks/vts reads.
// ---------------------------------------------------------------------------
__global__ __launch_bounds__(256, 2) void attn_mfma(
    const _Float16* __restrict__ qfu,  // [bh][1024][64]  (q+b+u)*0.125
    const _Float16* __restrict__ kf,   // [bh][2048][64]
    const _Float16* __restrict__ vfT,  // [bh][64][2048]
    const _Float16* __restrict__ rf,   // [h][2048][64]
    const float* __restrict__ u,       // [16][64]
    const float* __restrict__ v,       // [16][64]
    _Float16* __restrict__ attn_out)   // [i*4+b][1024] f16
{
  __shared__ _Float16 ks[64 * 64];        // [j][d] swizzled
  __shared__ _Float16 vts[64 * 64];       // [d][j] swizzled
  __shared__ _Float16 rs[256 * 64];       // ring (slot = m & 255), swizzled
  __shared__ _Float16 pA[2][4][16 * 64];  // per-group, per-wave probs

  const int t = threadIdx.x, w = t >> 6, l = t & 63;
  const int l15 = l & 15, l4 = l >> 4;
  const int id = blockIdx.x;
  // XCD swizzle on id&63; qt in [0,8): first 256 ids heavy (bx 7..4),
  // second 256 light (bx 0..3) so (id, id+256) pairs sum njt = 50.
  const int bh = ((id >> 3) & 7) * 8 + (id & 7);
  const int qt = id >> 6;
  const int bx = (qt < 4) ? (7 - qt) : (qt - 4);
  const int i0 = bx * 128;
  const int h = bh & 15, b = bh >> 4;

  const char* kfb = (const char*)(kf + (((size_t)bh * 2048) << 6));
  const char* vg = (const char*)(vfT + (((size_t)bh) << 17));
  const char* rg = (const char*)(rf + (((size_t)h) << 17));

  // q fragments for both groups; qv = qa + (v-u)*0.125 in-register
  half8 qa0[2], qa1[2], qv0[2], qv1[2];
  {
    half8 dl0, dl1;
#pragma unroll
    for (int z = 0; z < 8; ++z) {
      const int di = l4 * 8 + z;
      dl0[z] = (_Float16)(0.125f * (v[h * 64 + di] - u[h * 64 + di]));
      dl1[z] = (_Float16)(0.125f * (v[h * 64 + 32 + di] - u[h * 64 + 32 + di]));
    }
#pragma unroll
    for (int g = 0; g < 2; ++g) {
      const size_t qo =
          (((size_t)bh * 1024 + i0 + 64 * g + w * 16 + l15) << 6) + l4 * 8;
      qa0[g] = *(const half8*)(qfu + qo);
      qa1[g] = *(const half8*)(qfu + qo + 32);
      qv0[g] = qa0[g] + dl0;
      qv1[g] = qa1[g] + dl1;
    }
  }
  const f32x4 z4 = {0.f, 0.f, 0.f, 0.f};
  f32x4 o[2][4];
  float lsum[2][4];
#pragma unroll
  for (int g = 0; g < 2; ++g)
#pragma unroll
    for (int nt = 0; nt < 4; ++nt) { o[g][nt] = z4; lsum[g][nt] = 0.f; }

  const int mb0 = 960 - i0;  // group0 m_base at jt=0 (>= 64; mb0-64 >= 0)
  const int njt = 2 * bx + 18;

  // ---- prologue: stage initial 192-row r window [mb0-64, mb0+128) ----
#pragma unroll
  for (int iss = 0; iss < 6; ++iss) {
    const int off = w * 1024 + iss * 4096 + l * 16;
    const int q = off >> 7;  // 0..191
    const int cph = (off >> 4) & 7;
    const int slot = (mb0 - 64 + q) & 255;
    int m = mb0 - 64 + q;
    m = m < 2047 ? m : 2047;
    load_lds16(rg + (size_t)m * 128 + ((cph ^ (slot & 7)) << 4),
               (char*)rs + slot * 128 + cph * 16);
  }

  for (int jt = 0; jt < njt; ++jt) {
    const int j0 = jt * 64;
    const int m_base = j0 - i0 + 960;  // group0 base
    __syncthreads();  // prior tile's reads done before overwrite
    // ---- stage K, V^T (swizzled source) ----
    {
      const char* kg = kfb + (size_t)j0 * 128;
#pragma unroll
      for (int iss = 0; iss < 2; ++iss) {
        const int off = w * 1024 + iss * 4096 + l * 16;
        const int row = off >> 7;
        const int cph = (off >> 4) & 7;
        const int sw = ((cph ^ (row & 7)) << 4);
        load_lds16(kg + (size_t)row * 128 + sw, (char*)ks + off);
        load_lds16(vg + (size_t)row * 4096 + (size_t)j0 * 2 + sw,
                   (char*)vts + off);
      }
    }
    // ---- stage 64 new r rows [m_base+64, m_base+128) into ring ----
    if (jt > 0) {
      const int m0 = m_base + 64;
#pragma unroll
      for (int iss = 0; iss < 2; ++iss) {
        const int off = w * 1024 + iss * 4096 + l * 16;
        const int q = off >> 7;  // 0..63
        const int cph = (off >> 4) & 7;
        const int slot = (m0 + q) & 255;
        int m = m0 + q;
        m = m < 2047 ? m : 2047;
        load_lds16(rg + (size_t)m * 128 + ((cph ^ (slot & 7)) << 4),
                   (char*)rs + slot * 128 + cph * 16);
      }
    }
    __syncthreads();

    // ---- content scores: shared ks reads feed both groups ----
    f32x4 sc[2][4];
    __builtin_amdgcn_s_setprio(1);
#pragma unroll
    for (int nt = 0; nt < 4; ++nt) {
      const int row = nt * 16 + l15;
      const int rsw = row & 7;
      const half8 b0 = *(const half8*)&ks[row * 64 + ((l4 ^ rsw) * 8)];
      const half8 b1 = *(const half8*)&ks[row * 64 + (((4 + l4) ^ rsw) * 8)];
#pragma unroll
      for (int g = 0; g < 2; ++g) {
        f32x4 cc = z4;
        cc = __builtin_amdgcn_mfma_f32_16x16x32_f16(qa0[g], b0, cc, 0, 0, 0);
        cc = __builtin_amdgcn_mfma_f32_16x16x32_f16(qa1[g], b1, cc, 0, 0, 0);
        sc[g][nt] = cc;
      }
    }
    __builtin_amdgcn_s_setprio(0);

    // ---- per group: position scores + softmax ----
#pragma unroll
    for (int g = 0; g < 2; ++g) {
      const int cw = i0 + 64 * g - j0 + 1024 + 16 * w;
      if (g == 0 && cw < -15) continue;  // group0 fully masked (tail tile)
      const int mbg = m_base - 64 * g;
      f32x4 accP[5];
      __builtin_amdgcn_s_setprio(1);
#pragma unroll
      for (int p = 0; p < 5; ++p) {
        const int m = mbg + (3 - w + p) * 16 + l15;
        const int slot = m & 255;
        const int ssw = slot & 7;
        const half8 b0 = *(const half8*)&rs[slot * 64 + ((l4 ^ ssw) * 8)];
        const half8 b1 = *(const half8*)&rs[slot * 64 + (((4 + l4) ^ ssw) * 8)];
        f32x4 cc = z4;
        cc = __builtin_amdgcn_mfma_f32_16x16x32_f16(qv0[g], b0, cc, 0, 0, 0);
        cc = __builtin_amdgcn_mfma_f32_16x16x32_f16(qv1[g], b1, cc, 0, 0, 0);
        accP[p] = cc;
      }
      __builtin_amdgcn_s_setprio(0);
      if (cw >= 63) {  // wave-uniform: no masking possible in this tile
#pragma unroll
        for (int r = 0; r < 4; ++r) {
          const int thr = 4 * l4 + r;
          const int srcl = (l4 << 4) | ((15 + l15 - thr) & 15);
          float rot[5];
#pragma unroll
          for (int p = 0; p < 5; ++p) rot[p] = __shfl(accP[p][r], srcl, 64);
          float esum = 0.f;
          const int sw2 = (thr & 7) * 8;
#pragma unroll
          for (int nt = 0; nt < 4; ++nt) {
            const float pv = (l15 <= thr) ? rot[nt] : rot[nt + 1];
            const float e = __expf(sc[g][nt][r] + pv);
            esum += e;
            pA[g][w][thr * 64 + ((16 * nt + l15) ^ sw2)] = (_Float16)e;
          }
          lsum[g][r] += esum;
        }
      } else {
#pragma unroll
        for (int r = 0; r < 4; ++r) {
          const int thr = 4 * l4 + r;
          const int srcl = (l4 << 4) | ((15 + l15 - thr) & 15);
          float rot[5];
#pragma unroll
          for (int p = 0; p < 5; ++p) rot[p] = __shfl(accP[p][r], srcl, 64);
          float esum = 0.f;
          const int sw2 = (thr & 7) * 8;
#pragma unroll
          for (int nt = 0; nt < 4; ++nt) {
            const float pv = (l15 <= thr) ? rot[nt] : rot[nt + 1];
            const bool masked = (16 * nt + l15) > (cw + thr);
            const float e = masked ? 0.f : __expf(sc[g][nt][r] + pv);
            esum += e;
            pA[g][w][thr * 64 + ((16 * nt + l15) ^ sw2)] = (_Float16)e;
          }
          lsum[g][r] += esum;
        }
      }
    }

    // ---- PV: shared vts reads feed both groups ----
    const bool act0 = (i0 - j0 + 1024 + 16 * w) >= -15;
    __builtin_amdgcn_s_setprio(1);
#pragma unroll
    for (int kk = 0; kk < 2; ++kk) {
      const int aoff = l15 * 64 + ((kk * 32 + l4 * 8) ^ ((l15 & 7) * 8));
      half8 a81 = *(const half8*)&pA[1][w][aoff];
      half8 a80;
      if (act0) a80 = *(const half8*)&pA[0][w][aoff];
#pragma unroll
      for (int nt = 0; nt < 4; ++nt) {
        const int row = nt * 16 + l15;
        const half8 b8 =
            *(const half8*)&vts[row * 64 + ((((kk << 2) + l4) ^ (row & 7)) * 8)];
        if (act0)
          o[0][nt] =
              __builtin_amdgcn_mfma_f32_16x16x32_f16(a80, b8, o[0][nt], 0, 0, 0);
        o[1][nt] =
            __builtin_amdgcn_mfma_f32_16x16x32_f16(a81, b8, o[1][nt], 0, 0, 0);
      }
    }
    __builtin_amdgcn_s_setprio(0);
  }

  // ---- epilogue ----
#pragma unroll
  for (int g = 0; g < 2; ++g)
#pragma unroll
    for (int r = 0; r < 4; ++r) {
      float s = lsum[g][r];
      s += __shfl_xor(s, 1, 64);
      s += __shfl_xor(s, 2, 64);
      s += __shfl_xor(s, 4, 64);
      s += __shfl_xor(s, 8, 64);
      const float inv = 1.0f / s;
      const int i = i0 + 64 * g + w * 16 + l4 * 4 + r;
      const size_t base = ((size_t)i * 4 + b) * 1024 + h * 64;
#pragma unroll
      for (int nt = 0; nt < 4; ++nt)
        attn_out[base + nt * 16 + l15] = (_Float16)(o[g][nt][r] * inv);
    }
}

// ---------------------------------------------------------------------------
extern "C" void kernel_launch(void* const* d_in, const int* in_sizes, int n_in,
                              void* d_out, int out_size, void* d_ws,
                              size_t ws_size, hipStream_t stream) {
  const float* inputs   = (const float*)d_in[0];
  const float* pos_emb  = (const float*)d_in[1];
  const float* full_inp = (const float*)d_in[2];
  const float* u        = (const float*)d_in[3];
  const float* v        = (const float*)d_in[4];
  const float* W_kv   = (const float*)d_in[6];
  const float* b_kv   = (const float*)d_in[7];
  const float* W_q    = (const float*)d_in[8];
  const float* b_q    = (const float*)d_in[9];
  const float* W_pos  = (const float*)d_in[10];
  const float* b_pos  = (const float*)d_in[11];
  const float* W_proj = (const float*)d_in[12];
  const float* b_proj = (const float*)d_in[13];
  float* out = (float*)d_out;

  char* ws = (char*)d_ws;
  const size_t MB = 1024 * 1024;
  _Float16* in_q_h    = (_Float16*)(ws);            // 8 MB  (b-major 4096x1024)
  _Float16* in_full_h = (_Float16*)(ws + 8 * MB);   // 16 MB (b-major 8192x1024)
  _Float16* in_pos_h  = (_Float16*)(ws + 24 * MB);  // 4 MB  (2048x1024)
  _Float16* attn_h    = (_Float16*)(ws + 28 * MB);  // 8 MB  (4096x1024)
  _Float16* wq_t      = (_Float16*)(ws + 36 * MB);  // 2 MB
  _Float16* wkv_t     = (_Float16*)(ws + 38 * MB);  // 4 MB
  _Float16* wpos_t    = (_Float16*)(ws + 42 * MB);  // 2 MB
  _Float16* wproj_t   = (_Float16*)(ws + 44 * MB);  // 2 MB
  _Float16* qfu       = (_Float16*)(ws + 46 * MB);  // 8 MB  [bh][1024][64]
  _Float16* kf        = (_Float16*)(ws + 54 * MB);  // 16 MB [bh][2048][64]
  _Float16* vfT       = (_Float16*)(ws + 70 * MB);  // 16 MB [bh][64][2048]
  _Float16* rf        = (_Float16*)(ws + 86 * MB);  // 4 MB  [h][2048][64]

  const dim3 blk(256);
  prep<<<dim3(3328), blk, 0, stream>>>(inputs, full_inp, pos_emb, W_q, W_kv,
                                       W_pos, W_proj, in_q_h, in_full_h,
                                       in_pos_h, wq_t, wkv_t, wpos_t, wproj_t);
  gemm3<<<dim3(1408), blk, 0, stream>>>(in_q_h, in_full_h, in_pos_h, wq_t,
                                        wkv_t, wpos_t, b_q, b_kv, b_pos, u,
                                        qfu, kf, vfT, rf);
  attn_mfma<<<dim3(512), blk, 0, stream>>>(qfu, kf, vfT, rf, u, v, attn_h);
  gemm_proj<<<dim3(16, 32), blk, 0, stream>>>(attn_h, wproj_t, b_proj, out,
                                              4096, 1024, 1024);
}

// Round 9
// 327.398 us; speedup vs baseline: 1.1659x; 1.0268x over previous
//
#include <hip/hip_runtime.h>

// AttentionXL: CUR=1024, FULL=2048, BS=4, D=1024, HN=16, HD=64, PREV=1024
// f16 MFMA 16x16x32 everywhere; fp32 accumulate/softmax.
// Scores pre-scaled: qfu = (q+b+u)*0.125; qv = qfu + (v-u)*0.125 in-register.

typedef _Float16 half8 __attribute__((ext_vector_type(8)));
typedef _Float16 half4v __attribute__((ext_vector_type(4)));
typedef float f32x4 __attribute__((ext_vector_type(4)));

typedef const __attribute__((address_space(1))) void* gas_ptr;
typedef __attribute__((address_space(3))) void* las_ptr;

__device__ __forceinline__ void load_lds16(const void* g, void* l) {
  __builtin_amdgcn_global_load_lds((gas_ptr)g, (las_ptr)l, 16, 0, 0);
}

// ---------------------------------------------------------------------------
// prep v10: activation fp32->f16 grid-strided (2048 blocks x 7 iters, uniform
// branch per iter) + weight convert+transpose (blocks [2048,3328)).
// ---------------------------------------------------------------------------
__global__ __launch_bounds__(256) void prep(
    const float* __restrict__ inputs, const float* __restrict__ full_inp,
    const float* __restrict__ pos_emb, const float* __restrict__ Wq,
    const float* __restrict__ Wkv, const float* __restrict__ Wpos,
    const float* __restrict__ Wproj, _Float16* __restrict__ o_in,
    _Float16* __restrict__ o_full, _Float16* __restrict__ o_pos,
    _Float16* __restrict__ owq, _Float16* __restrict__ owkv,
    _Float16* __restrict__ owpos, _Float16* __restrict__ owproj) {
  __shared__ _Float16 tile[64][65];
  const int bx = blockIdx.x;
  const int t = threadIdx.x;
  if (bx < 2048) {
#pragma unroll
    for (int it = 0; it < 7; ++it) {
      const size_t g = (size_t)bx * 256 + t + (size_t)it * (2048 * 256);
      float4 vv;
      _Float16* dptr;
      if (g < (1u << 20)) {  // inputs -> in_q_h, b-major
        const int rd = (int)(g >> 8), b = rd >> 10, i = rd & 1023;
        const size_t sg = ((size_t)(i * 4 + b) << 8) + (g & 255);
        vv = *(const float4*)(inputs + sg * 4);
        dptr = o_in + g * 4;
      } else if (g < (3u << 20)) {  // full_inp -> in_full_h, b-major
        const size_t gd = g - (1u << 20);
        const int rd = (int)(gd >> 8), b = rd >> 11, j = rd & 2047;
        const size_t sg = ((size_t)(j * 4 + b) << 8) + (gd & 255);
        vv = *(const float4*)(full_inp + sg * 4);
        dptr = o_full + gd * 4;
      } else {  // pos_emb plain
        const size_t gd = g - (3u << 20);
        vv = *(const float4*)(pos_emb + gd * 4);
        dptr = o_pos + gd * 4;
      }
      half4v hh;
      hh[0] = (_Float16)vv.x; hh[1] = (_Float16)vv.y;
      hh[2] = (_Float16)vv.z; hh[3] = (_Float16)vv.w;
      *(half4v*)dptr = hh;
    }
    return;
  }
  const int wb = bx - 2048;
  const float* W;
  _Float16* Wt;
  int N, tidx;
  if (wb < 256) { W = Wq; Wt = owq; N = 1024; tidx = wb; }
  else if (wb < 768) { W = Wkv; Wt = owkv; N = 2048; tidx = wb - 256; }
  else if (wb < 1024) { W = Wpos; Wt = owpos; N = 1024; tidx = wb - 768; }
  else { W = Wproj; Wt = owproj; N = 1024; tidx = wb - 1024; }
  const int K = 1024;
  const int n0 = (tidx % (N >> 6)) * 64, k0 = (tidx / (N >> 6)) * 64;
  const int rr = t >> 2, cc = (t & 3) * 16;
#pragma unroll
  for (int i = 0; i < 4; ++i) {
    float4 v = *(const float4*)&W[(size_t)(k0 + rr) * N + n0 + cc + i * 4];
    tile[rr][cc + i * 4 + 0] = (_Float16)v.x;
    tile[rr][cc + i * 4 + 1] = (_Float16)v.y;
    tile[rr][cc + i * 4 + 2] = (_Float16)v.z;
    tile[rr][cc + i * 4 + 3] = (_Float16)v.w;
  }
  __syncthreads();
  const int n = t >> 2, kc = (t & 3) * 16;
#pragma unroll
  for (int i = 0; i < 4; ++i) {
    half4v h;
    h[0] = tile[kc + i * 4 + 0][n];
    h[1] = tile[kc + i * 4 + 1][n];
    h[2] = tile[kc + i * 4 + 2][n];
    h[3] = tile[kc + i * 4 + 3][n];
    *(half4v*)&Wt[(size_t)(n0 + n) * K + k0 + kc + i * 4] = h;
  }
}

// ---------------------------------------------------------------------------
// Fused q/kv/r GEMM v13 (A matrices are b-major). 1408 blocks.
//  BK=64, XOR-swizzled staging + fragment reads; DOUBLE-BUFFERED pipeline:
//  stage(k+1) issued -> compute(k) -> one vmcnt-drain barrier per k-step
//  (v8-attn-verified choreography). gemm3's k-step has only ~320 cyc of MFMA
//  vs ~600-900 cyc staging latency, so the old sync->stage->sync->compute
//  structure exposed the full drain every step.
//  LDS 64 KB: As0@0 | Bs0@16K | As1@32K | Bs1@48K (bytes); epilogue
//  V-transpose reuses buffer region after the final barrier.
// ---------------------------------------------------------------------------
__global__ __launch_bounds__(256, 2) void gemm3(
    const _Float16* __restrict__ Aq, const _Float16* __restrict__ Akv,
    const _Float16* __restrict__ Ar, const _Float16* __restrict__ Btq,
    const _Float16* __restrict__ Btkv, const _Float16* __restrict__ Btr,
    const float* __restrict__ bq, const float* __restrict__ bkv,
    const float* __restrict__ br, const float* __restrict__ uu,
    _Float16* __restrict__ qfu, _Float16* __restrict__ kf,
    _Float16* __restrict__ vfT, _Float16* __restrict__ rf) {
  __shared__ _Float16 smem[32768];  // 64 KB
  const int gb = blockIdx.x;
  const _Float16* A;
  const _Float16* Bt;
  const float* bias;
  int mode, bm, bn;
  if (gb < 256) {
    mode = 1; A = Aq; Bt = Btq; bias = bq;
    bn = (gb & 7) * 128; bm = (gb >> 3) * 128;
  } else if (gb < 1280) {
    mode = 2; A = Akv; Bt = Btkv; bias = bkv;
    const int j = gb - 256;
    bn = (j & 15) * 128; bm = (j >> 4) * 128;
  } else {
    mode = 3; A = Ar; Bt = Btr; bias = br;
    const int j = gb - 1280;
    bn = (j & 7) * 128; bm = (j >> 3) * 128;
  }
  const int K = 1024;
  const int t = threadIdx.x, w = t >> 6, l = t & 63;
  const int l15 = l & 15, l4 = l >> 4;
  const int wm = (w >> 1) * 64, wn = (w & 1) * 64;

  f32x4 acc[4][4];
  const f32x4 z4 = {0.f, 0.f, 0.f, 0.f};
#pragma unroll
  for (int i = 0; i < 4; ++i)
#pragma unroll
    for (int j = 0; j < 4; ++j) acc[i][j] = z4;

  const char* Abase = (const char*)A + (size_t)bm * K * 2;
  const char* Bbase = (const char*)Bt + (size_t)bn * K * 2;

  // ---- prologue: stage k0=0 into buffer 0 ----
#pragma unroll
  for (int iss = 0; iss < 4; ++iss) {
    const int off = w * 4096 + iss * 1024 + l * 16;
    const int row = off >> 7;
    const int sw = ((((off >> 4) & 7) ^ (row & 7)) << 4);
    load_lds16(Abase + (size_t)row * (K * 2) + sw, (char*)smem + off);
    load_lds16(Bbase + (size_t)row * (K * 2) + sw, (char*)smem + 16384 + off);
  }
  __syncthreads();

  int cur = 0;
  for (int k0 = 0; k0 < K; k0 += 64) {
    // ---- issue next-step staging (flies under this step's MFMAs) ----
    if (k0 + 64 < K) {
      const int nb = cur ^ 1;
#pragma unroll
      for (int iss = 0; iss < 4; ++iss) {
        const int off = w * 4096 + iss * 1024 + l * 16;
        const int row = off >> 7;
        const int sw = ((((off >> 4) & 7) ^ (row & 7)) << 4);
        load_lds16(Abase + (size_t)row * (K * 2) + (k0 + 64) * 2 + sw,
                   (char*)smem + nb * 32768 + off);
        load_lds16(Bbase + (size_t)row * (K * 2) + (k0 + 64) * 2 + sw,
                   (char*)smem + nb * 32768 + 16384 + off);
      }
    }
    const _Float16* Asc = smem + cur * 16384;
    const _Float16* Bsc = smem + cur * 16384 + 8192;
#pragma unroll
    for (int ks = 0; ks < 2; ++ks) {
      const int ch = ((ks * 4 + l4) ^ (l15 & 7)) * 8;
      half8 af[4], bf[4];
#pragma unroll
      for (int mt = 0; mt < 4; ++mt)
        af[mt] = *(const half8*)&Asc[(wm + mt * 16 + l15) * 64 + ch];
#pragma unroll
      for (int nt = 0; nt < 4; ++nt)
        bf[nt] = *(const half8*)&Bsc[(wn + nt * 16 + l15) * 64 + ch];
#pragma unroll
      for (int mt = 0; mt < 4; ++mt)
#pragma unroll
        for (int nt = 0; nt < 4; ++nt)
          acc[mt][nt] = __builtin_amdgcn_mfma_f32_16x16x32_f16(
              af[mt], bf[nt], acc[mt][nt], 0, 0, 0);
    }
    __syncthreads();  // single per-step drain: stage(k+1) lands AFTER compute
    cur ^= 1;
  }

  if (mode == 2 && bn >= 1024) {
    // ---- V half: LDS transpose -> coalesced vfT[bh][d][j] stores ----
    const int b = bm >> 11, j0m = bm & 2047;
    const int hbase = (bn - 1024) >> 6;  // even
#pragma unroll
    for (int ch = 0; ch < 2; ++ch) {
      __syncthreads();
      if (((wn >> 6) & 1) == ch) {
#pragma unroll
        for (int mt = 0; mt < 4; ++mt)
#pragma unroll
          for (int r = 0; r < 4; ++r) {
            const int rowl = wm + mt * 16 + l4 * 4 + r;
#pragma unroll
            for (int nt = 0; nt < 4; ++nt) {
              const int coll = nt * 16 + l15;
              smem[rowl * 66 + coll] =
                  (_Float16)(acc[mt][nt][r] + bias[bn + wn + coll]);
            }
          }
      }
      __syncthreads();
#pragma unroll
      for (int it = 0; it < 4; ++it) {
        const int c = t + 256 * it;
        const int d = c >> 4, ck = c & 15;
        half8 v8;
#pragma unroll
        for (int z = 0; z < 8; ++z) v8[z] = smem[(ck * 8 + z) * 66 + d];
        *(half8*)&vfT[(((size_t)(b * 16 + hbase + ch) * 64 + d) << 11) + j0m +
                      ck * 8] = v8;
      }
    }
    return;
  }

#pragma unroll
  for (int mt = 0; mt < 4; ++mt)
#pragma unroll
    for (int r = 0; r < 4; ++r) {
      const int rowl = wm + mt * 16 + l4 * 4 + r;
#pragma unroll
      for (int nt = 0; nt < 4; ++nt) {
        const int col = bn + wn + nt * 16 + l15;
        const float val = acc[mt][nt][r] + bias[col];
        if (mode == 1) {
          const int b = bm >> 10, i0m = bm & 1023;
          const int h = col >> 6, d = col & 63;
          qfu[(((size_t)(b * 16 + h) * 1024 + i0m + rowl) << 6) + d] =
              (_Float16)((val + uu[col]) * 0.125f);
        } else if (mode == 2) {
          const int b = bm >> 11, j0m = bm & 2047;
          const int h = col >> 6, d = col & 63;
          kf[(((size_t)(b * 16 + h) * 2048 + j0m + rowl) << 6) + d] =
              (_Float16)val;
        } else {
          const int h = col >> 6, d = col & 63;
          rf[(((size_t)h * 2048 + bm + rowl) << 6) + d] = (_Float16)val;
        }
      }
    }
}

// ---------------------------------------------------------------------------
// proj GEMM v13: out f32 [M][N] = A @ Bt^T + bias. 128x64 tiles, 512 blocks;
// double-buffered (48 KB LDS: As0@0 | Bs0@16K | As1@24K | Bs1@40K bytes).
// ---------------------------------------------------------------------------
__global__ __launch_bounds__(256, 2) void gemm_proj(
    const _Float16* __restrict__ A, const _Float16* __restrict__ Bt,
    const float* __restrict__ bias, float* __restrict__ out0, int M, int N,
    int K) {
  __shared__ _Float16 smem[24576];  // 48 KB
  const int t = threadIdx.x, w = t >> 6, l = t & 63;
  const int l15 = l & 15, l4 = l >> 4;
  const int bm = blockIdx.y * 128, bn = blockIdx.x * 64;
  const int wm = (w >> 1) * 64, wn = (w & 1) * 32;

  f32x4 acc[4][2];
  const f32x4 z4 = {0.f, 0.f, 0.f, 0.f};
#pragma unroll
  for (int i = 0; i < 4; ++i)
#pragma unroll
    for (int j = 0; j < 2; ++j) acc[i][j] = z4;

  const char* Abase = (const char*)A + (size_t)bm * K * 2;
  const char* Bbase = (const char*)Bt + (size_t)bn * K * 2;

  // ---- prologue: stage k0=0 into buffer 0 ----
#pragma unroll
  for (int iss = 0; iss < 4; ++iss) {
    const int off = w * 4096 + iss * 1024 + l * 16;
    const int row = off >> 7;
    const int sw = ((((off >> 4) & 7) ^ (row & 7)) << 4);
    load_lds16(Abase + (size_t)row * (K * 2) + sw, (char*)smem + off);
  }
#pragma unroll
  for (int iss = 0; iss < 2; ++iss) {
    const int off = w * 1024 + iss * 4096 + l * 16;
    const int row = off >> 7;
    const int sw = ((((off >> 4) & 7) ^ (row & 7)) << 4);
    load_lds16(Bbase + (size_t)row * (K * 2) + sw, (char*)smem + 16384 + off);
  }
  __syncthreads();

  int cur = 0;
  for (int k0 = 0; k0 < K; k0 += 64) {
    if (k0 + 64 < K) {
      const int nb = cur ^ 1;
#pragma unroll
      for (int iss = 0; iss < 4; ++iss) {
        const int off = w * 4096 + iss * 1024 + l * 16;
        const int row = off >> 7;
        const int sw = ((((off >> 4) & 7) ^ (row & 7)) << 4);
        load_lds16(Abase + (size_t)row * (K * 2) + (k0 + 64) * 2 + sw,
                   (char*)smem + nb * 24576 + off);
      }
#pragma unroll
      for (int iss = 0; iss < 2; ++iss) {
        const int off = w * 1024 + iss * 4096 + l * 16;
        const int row = off >> 7;
        const int sw = ((((off >> 4) & 7) ^ (row & 7)) << 4);
        load_lds16(Bbase + (size_t)row * (K * 2) + (k0 + 64) * 2 + sw,
                   (char*)smem + nb * 24576 + 16384 + off);
      }
    }
    const _Float16* Asc = smem + cur * 12288;
    const _Float16* Bsc = smem + cur * 12288 + 8192;
#pragma unroll
    for (int ks = 0; ks < 2; ++ks) {
      const int ch = ((ks * 4 + l4) ^ (l15 & 7)) * 8;
      half8 af[4], bf[2];
#pragma unroll
      for (int mt = 0; mt < 4; ++mt)
        af[mt] = *(const half8*)&Asc[(wm + mt * 16 + l15) * 64 + ch];
#pragma unroll
      for (int nt = 0; nt < 2; ++nt)
        bf[nt] = *(const half8*)&Bsc[(wn + nt * 16 + l15) * 64 + ch];
#pragma unroll
      for (int mt = 0; mt < 4; ++mt)
#pragma unroll
        for (int nt = 0; nt < 2; ++nt)
          acc[mt][nt] = __builtin_amdgcn_mfma_f32_16x16x32_f16(
              af[mt], bf[nt], acc[mt][nt], 0, 0, 0);
    }
    __syncthreads();
    cur ^= 1;
  }

#pragma unroll
  for (int mt = 0; mt < 4; ++mt)
#pragma unroll
    for (int r = 0; r < 4; ++r) {
      const int row = bm + wm + mt * 16 + l4 * 4 + r;
#pragma unroll
      for (int nt = 0; nt < 2; ++nt) {
        const int col = bn + wn + nt * 16 + l15;
        out0[(size_t)row * N + col] = acc[mt][nt][r] + bias[col];
      }
    }
}

// ---------------------------------------------------------------------------
// MFMA flash attention v9 (verified 101.9 us): 128 q-rows per block
// (2 row-groups per wave), shared ks/vts fragment reads feed both groups.
// ---------------------------------------------------------------------------
__global__ __launch_bounds__(256, 2) void attn_mfma(
    const _Float16* __restrict__ qfu,  // [bh][1024][64]  (q+b+u)*0.125
    const _Float16* __restrict__ kf,   // [bh][2048][64]
    const _Float16* __restrict__ vfT,  // [bh][64][2048]
    const _Float16* __restrict__ rf,   // [h][2048][64]
    const float* __restrict__ u,       // [16][64]
    const float* __restrict__ v,       // [16][64]
    _Float16* __restrict__ attn_out)   // [i*4+b][1024] f16
{
  __shared__ _Float16 ks[64 * 64];        // [j][d] swizzled
  __shared__ _Float16 vts[64 * 64];       // [d][j] swizzled
  __shared__ _Float16 rs[256 * 64];       // ring (slot = m & 255), swizzled
  __shared__ _Float16 pA[2][4][16 * 64];  // per-group, per-wave probs

  const int t = threadIdx.x, w = t >> 6, l = t & 63;
  const int l15 = l & 15, l4 = l >> 4;
  const int id = blockIdx.x;
  // XCD swizzle on id&63; qt in [0,8): first 256 ids heavy (bx 7..4),
  // second 256 light (bx 0..3) so (id, id+256) pairs sum njt = 50.
  const int bh = ((id >> 3) & 7) * 8 + (id & 7);
  const int qt = id >> 6;
  const int bx = (qt < 4) ? (7 - qt) : (qt - 4);
  const int i0 = bx * 128;
  const int h = bh & 15, b = bh >> 4;

  const char* kfb = (const char*)(kf + (((size_t)bh * 2048) << 6));
  const char* vg = (const char*)(vfT + (((size_t)bh) << 17));
  const char* rg = (const char*)(rf + (((size_t)h) << 17));

  // q fragments for both groups; qv = qa + (v-u)*0.125 in-register
  half8 qa0[2], qa1[2], qv0[2], qv1[2];
  {
    half8 dl0, dl1;
#pragma unroll
    for (int z = 0; z < 8; ++z) {
      const int di = l4 * 8 + z;
      dl0[z] = (_Float16)(0.125f * (v[h * 64 + di] - u[h * 64 + di]));
      dl1[z] = (_Float16)(0.125f * (v[h * 64 + 32 + di] - u[h * 64 + 32 + di]));
    }
#pragma unroll
    for (int g = 0; g < 2; ++g) {
      const size_t qo =
          (((size_t)bh * 1024 + i0 + 64 * g + w * 16 + l15) << 6) + l4 * 8;
      qa0[g] = *(const half8*)(qfu + qo);
      qa1[g] = *(const half8*)(qfu + qo + 32);
      qv0[g] = qa0[g] + dl0;
      qv1[g] = qa1[g] + dl1;
    }
  }
  const f32x4 z4 = {0.f, 0.f, 0.f, 0.f};
  f32x4 o[2][4];
  float lsum[2][4];
#pragma unroll
  for (int g = 0; g < 2; ++g)
#pragma unroll
    for (int nt = 0; nt < 4; ++nt) { o[g][nt] = z4; lsum[g][nt] = 0.f; }

  const int mb0 = 960 - i0;  // group0 m_base at jt=0 (>= 64; mb0-64 >= 0)
  const int njt = 2 * bx + 18;

  // ---- prologue: stage initial 192-row r window [mb0-64, mb0+128) ----
#pragma unroll
  for (int iss = 0; iss < 6; ++iss) {
    const int off = w * 1024 + iss * 4096 + l * 16;
    const int q = off >> 7;  // 0..191
    const int cph = (off >> 4) & 7;
    const int slot = (mb0 - 64 + q) & 255;
    int m = mb0 - 64 + q;
    m = m < 2047 ? m : 2047;
    load_lds16(rg + (size_t)m * 128 + ((cph ^ (slot & 7)) << 4),
               (char*)rs + slot * 128 + cph * 16);
  }

  for (int jt = 0; jt < njt; ++jt) {
    const int j0 = jt * 64;
    const int m_base = j0 - i0 + 960;  // group0 base
    __syncthreads();  // prior tile's reads done before overwrite
    // ---- stage K, V^T (swizzled source) ----
    {
      const char* kg = kfb + (size_t)j0 * 128;
#pragma unroll
      for (int iss = 0; iss < 2; ++iss) {
        const int off = w * 1024 + iss * 4096 + l * 16;
        const int row = off >> 7;
        const int cph = (off >> 4) & 7;
        const int sw = ((cph ^ (row & 7)) << 4);
        load_lds16(kg + (size_t)row * 128 + sw, (char*)ks + off);
        load_lds16(vg + (size_t)row * 4096 + (size_t)j0 * 2 + sw,
                   (char*)vts + off);
      }
    }
    // ---- stage 64 new r rows [m_base+64, m_base+128) into ring ----
    if (jt > 0) {
      const int m0 = m_base + 64;
#pragma unroll
      for (int iss = 0; iss < 2; ++iss) {
        const int off = w * 1024 + iss * 4096 + l * 16;
        const int q = off >> 7;  // 0..63
        const int cph = (off >> 4) & 7;
        const int slot = (m0 + q) & 255;
        int m = m0 + q;
        m = m < 2047 ? m : 2047;
        load_lds16(rg + (size_t)m * 128 + ((cph ^ (slot & 7)) << 4),
                   (char*)rs + slot * 128 + cph * 16);
      }
    }
    __syncthreads();

    // ---- content scores: shared ks reads feed both groups ----
    f32x4 sc[2][4];
#pragma unroll
    for (int nt = 0; nt < 4; ++nt) {
      const int row = nt * 16 + l15;
      const int rsw = row & 7;
      const half8 b0 = *(const half8*)&ks[row * 64 + ((l4 ^ rsw) * 8)];
      const half8 b1 = *(const half8*)&ks[row * 64 + (((4 + l4) ^ rsw) * 8)];
#pragma unroll
      for (int g = 0; g < 2; ++g) {
        f32x4 cc = z4;
        cc = __builtin_amdgcn_mfma_f32_16x16x32_f16(qa0[g], b0, cc, 0, 0, 0);
        cc = __builtin_amdgcn_mfma_f32_16x16x32_f16(qa1[g], b1, cc, 0, 0, 0);
        sc[g][nt] = cc;
      }
    }

    // ---- per group: position scores + softmax ----
#pragma unroll
    for (int g = 0; g < 2; ++g) {
      const int cw = i0 + 64 * g - j0 + 1024 + 16 * w;
      if (g == 0 && cw < -15) continue;  // group0 fully masked (tail tile)
      const int mbg = m_base - 64 * g;
      f32x4 accP[5];
#pragma unroll
      for (int p = 0; p < 5; ++p) {
        const int m = mbg + (3 - w + p) * 16 + l15;
        const int slot = m & 255;
        const int ssw = slot & 7;
        const half8 b0 = *(const half8*)&rs[slot * 64 + ((l4 ^ ssw) * 8)];
        const half8 b1 = *(const half8*)&rs[slot * 64 + (((4 + l4) ^ ssw) * 8)];
        f32x4 cc = z4;
        cc = __builtin_amdgcn_mfma_f32_16x16x32_f16(qv0[g], b0, cc, 0, 0, 0);
        cc = __builtin_amdgcn_mfma_f32_16x16x32_f16(qv1[g], b1, cc, 0, 0, 0);
        accP[p] = cc;
      }
      if (cw >= 63) {  // wave-uniform: no masking possible in this tile
#pragma unroll
        for (int r = 0; r < 4; ++r) {
          const int thr = 4 * l4 + r;
          const int srcl = (l4 << 4) | ((15 + l15 - thr) & 15);
          float rot[5];
#pragma unroll
          for (int p = 0; p < 5; ++p) rot[p] = __shfl(accP[p][r], srcl, 64);
          float esum = 0.f;
          const int sw2 = (thr & 7) * 8;
#pragma unroll
          for (int nt = 0; nt < 4; ++nt) {
            const float pv = (l15 <= thr) ? rot[nt] : rot[nt + 1];
            const float e = __expf(sc[g][nt][r] + pv);
            esum += e;
            pA[g][w][thr * 64 + ((16 * nt + l15) ^ sw2)] = (_Float16)e;
          }
          lsum[g][r] += esum;
        }
      } else {
#pragma unroll
        for (int r = 0; r < 4; ++r) {
          const int thr = 4 * l4 + r;
          const int srcl = (l4 << 4) | ((15 + l15 - thr) & 15);
          float rot[5];
#pragma unroll
          for (int p = 0; p < 5; ++p) rot[p] = __shfl(accP[p][r], srcl, 64);
          float esum = 0.f;
          const int sw2 = (thr & 7) * 8;
#pragma unroll
          for (int nt = 0; nt < 4; ++nt) {
            const float pv = (l15 <= thr) ? rot[nt] : rot[nt + 1];
            const bool masked = (16 * nt + l15) > (cw + thr);
            const float e = masked ? 0.f : __expf(sc[g][nt][r] + pv);
            esum += e;
            pA[g][w][thr * 64 + ((16 * nt + l15) ^ sw2)] = (_Float16)e;
          }
          lsum[g][r] += esum;
        }
      }
    }

    // ---- PV: shared vts reads feed both groups ----
    const bool act0 = (i0 - j0 + 1024 + 16 * w) >= -15;
#pragma unroll
    for (int kk = 0; kk < 2; ++kk) {
      const int aoff = l15 * 64 + ((kk * 32 + l4 * 8) ^ ((l15 & 7) * 8));
      half8 a81 = *(const half8*)&pA[1][w][aoff];
      half8 a80;
      if (act0) a80 = *(const half8*)&pA[0][w][aoff];
#pragma unroll
      for (int nt = 0; nt < 4; ++nt) {
        const int row = nt * 16 + l15;
        const half8 b8 =
            *(const half8*)&vts[row * 64 + ((((kk << 2) + l4) ^ (row & 7)) * 8)];
        if (act0)
          o[0][nt] =
              __builtin_amdgcn_mfma_f32_16x16x32_f16(a80, b8, o[0][nt], 0, 0, 0);
        o[1][nt] =
            __builtin_amdgcn_mfma_f32_16x16x32_f16(a81, b8, o[1][nt], 0, 0, 0);
      }
    }
  }

  // ---- epilogue ----
#pragma unroll
  for (int g = 0; g < 2; ++g)
#pragma unroll
    for (int r = 0; r < 4; ++r) {
      float s = lsum[g][r];
      s += __shfl_xor(s, 1, 64);
      s += __shfl_xor(s, 2, 64);
      s += __shfl_xor(s, 4, 64);
      s += __shfl_xor(s, 8, 64);
      const float inv = 1.0f / s;
      const int i = i0 + 64 * g + w * 16 + l4 * 4 + r;
      const size_t base = ((size_t)i * 4 + b) * 1024 + h * 64;
#pragma unroll
      for (int nt = 0; nt < 4; ++nt)
        attn_out[base + nt * 16 + l15] = (_Float16)(o[g][nt][r] * inv);
    }
}

// ---------------------------------------------------------------------------
extern "C" void kernel_launch(void* const* d_in, const int* in_sizes, int n_in,
                              void* d_out, int out_size, void* d_ws,
                              size_t ws_size, hipStream_t stream) {
  const float* inputs   = (const float*)d_in[0];
  const float* pos_emb  = (const float*)d_in[1];
  const float* full_inp = (const float*)d_in[2];
  const float* u        = (const float*)d_in[3];
  const float* v        = (const float*)d_in[4];
  const float* W_kv   = (const float*)d_in[6];
  const float* b_kv   = (const float*)d_in[7];
  const float* W_q    = (const float*)d_in[8];
  const float* b_q    = (const float*)d_in[9];
  const float* W_pos  = (const float*)d_in[10];
  const float* b_pos  = (const float*)d_in[11];
  const float* W_proj = (const float*)d_in[12];
  const float* b_proj = (const float*)d_in[13];
  float* out = (float*)d_out;

  char* ws = (char*)d_ws;
  const size_t MB = 1024 * 1024;
  _Float16* in_q_h    = (_Float16*)(ws);            // 8 MB  (b-major 4096x1024)
  _Float16* in_full_h = (_Float16*)(ws + 8 * MB);   // 16 MB (b-major 8192x1024)
  _Float16* in_pos_h  = (_Float16*)(ws + 24 * MB);  // 4 MB  (2048x1024)
  _Float16* attn_h    = (_Float16*)(ws + 28 * MB);  // 8 MB  (4096x1024)
  _Float16* wq_t      = (_Float16*)(ws + 36 * MB);  // 2 MB
  _Float16* wkv_t     = (_Float16*)(ws + 38 * MB);  // 4 MB
  _Float16* wpos_t    = (_Float16*)(ws + 42 * MB);  // 2 MB
  _Float16* wproj_t   = (_Float16*)(ws + 44 * MB);  // 2 MB
  _Float16* qfu       = (_Float16*)(ws + 46 * MB);  // 8 MB  [bh][1024][64]
  _Float16* kf        = (_Float16*)(ws + 54 * MB);  // 16 MB [bh][2048][64]
  _Float16* vfT       = (_Float16*)(ws + 70 * MB);  // 16 MB [bh][64][2048]
  _Float16* rf        = (_Float16*)(ws + 86 * MB);  // 4 MB  [h][2048][64]

  const dim3 blk(256);
  prep<<<dim3(3328), blk, 0, stream>>>(inputs, full_inp, pos_emb, W_q, W_kv,
                                       W_pos, W_proj, in_q_h, in_full_h,
                                       in_pos_h, wq_t, wkv_t, wpos_t, wproj_t);
  gemm3<<<dim3(1408), blk, 0, stream>>>(in_q_h, in_full_h, in_pos_h, wq_t,
                                        wkv_t, wpos_t, b_q, b_kv, b_pos, u,
                                        qfu, kf, vfT, rf);
  attn_mfma<<<dim3(512), blk, 0, stream>>>(qfu, kf, vfT, rf, u, v, attn_h);
  gemm_proj<<<dim3(16, 32), blk, 0, stream>>>(attn_h, wproj_t, b_proj, out,
                                              4096, 1024, 1024);
}

// Round 10
// 319.470 us; speedup vs baseline: 1.1948x; 1.0248x over previous
//
#include <hip/hip_runtime.h>

// AttentionXL: CUR=1024, FULL=2048, BS=4, D=1024, HN=16, HD=64, PREV=1024
// f16 MFMA 16x16x32 everywhere; fp32 accumulate/softmax.
// Scores pre-scaled: qfu = (q+b+u)*0.125; qv = qfu + (v-u)*0.125 in-register.

typedef _Float16 half8 __attribute__((ext_vector_type(8)));
typedef _Float16 half4v __attribute__((ext_vector_type(4)));
typedef float f32x4 __attribute__((ext_vector_type(4)));

typedef const __attribute__((address_space(1))) void* gas_ptr;
typedef __attribute__((address_space(3))) void* las_ptr;

__device__ __forceinline__ void load_lds16(const void* g, void* l) {
  __builtin_amdgcn_global_load_lds((gas_ptr)g, (las_ptr)l, 16, 0, 0);
}

// ---------------------------------------------------------------------------
// prep v10: activation fp32->f16 grid-strided (2048 blocks x 7 iters, uniform
// branch per iter) + weight convert+transpose (blocks [2048,3328)).
// ---------------------------------------------------------------------------
__global__ __launch_bounds__(256) void prep(
    const float* __restrict__ inputs, const float* __restrict__ full_inp,
    const float* __restrict__ pos_emb, const float* __restrict__ Wq,
    const float* __restrict__ Wkv, const float* __restrict__ Wpos,
    const float* __restrict__ Wproj, _Float16* __restrict__ o_in,
    _Float16* __restrict__ o_full, _Float16* __restrict__ o_pos,
    _Float16* __restrict__ owq, _Float16* __restrict__ owkv,
    _Float16* __restrict__ owpos, _Float16* __restrict__ owproj) {
  __shared__ _Float16 tile[64][65];
  const int bx = blockIdx.x;
  const int t = threadIdx.x;
  if (bx < 2048) {
#pragma unroll
    for (int it = 0; it < 7; ++it) {
      const size_t g = (size_t)bx * 256 + t + (size_t)it * (2048 * 256);
      float4 vv;
      _Float16* dptr;
      if (g < (1u << 20)) {  // inputs -> in_q_h, b-major
        const int rd = (int)(g >> 8), b = rd >> 10, i = rd & 1023;
        const size_t sg = ((size_t)(i * 4 + b) << 8) + (g & 255);
        vv = *(const float4*)(inputs + sg * 4);
        dptr = o_in + g * 4;
      } else if (g < (3u << 20)) {  // full_inp -> in_full_h, b-major
        const size_t gd = g - (1u << 20);
        const int rd = (int)(gd >> 8), b = rd >> 11, j = rd & 2047;
        const size_t sg = ((size_t)(j * 4 + b) << 8) + (gd & 255);
        vv = *(const float4*)(full_inp + sg * 4);
        dptr = o_full + gd * 4;
      } else {  // pos_emb plain
        const size_t gd = g - (3u << 20);
        vv = *(const float4*)(pos_emb + gd * 4);
        dptr = o_pos + gd * 4;
      }
      half4v hh;
      hh[0] = (_Float16)vv.x; hh[1] = (_Float16)vv.y;
      hh[2] = (_Float16)vv.z; hh[3] = (_Float16)vv.w;
      *(half4v*)dptr = hh;
    }
    return;
  }
  const int wb = bx - 2048;
  const float* W;
  _Float16* Wt;
  int N, tidx;
  if (wb < 256) { W = Wq; Wt = owq; N = 1024; tidx = wb; }
  else if (wb < 768) { W = Wkv; Wt = owkv; N = 2048; tidx = wb - 256; }
  else if (wb < 1024) { W = Wpos; Wt = owpos; N = 1024; tidx = wb - 768; }
  else { W = Wproj; Wt = owproj; N = 1024; tidx = wb - 1024; }
  const int K = 1024;
  const int n0 = (tidx % (N >> 6)) * 64, k0 = (tidx / (N >> 6)) * 64;
  const int rr = t >> 2, cc = (t & 3) * 16;
#pragma unroll
  for (int i = 0; i < 4; ++i) {
    float4 v = *(const float4*)&W[(size_t)(k0 + rr) * N + n0 + cc + i * 4];
    tile[rr][cc + i * 4 + 0] = (_Float16)v.x;
    tile[rr][cc + i * 4 + 1] = (_Float16)v.y;
    tile[rr][cc + i * 4 + 2] = (_Float16)v.z;
    tile[rr][cc + i * 4 + 3] = (_Float16)v.w;
  }
  __syncthreads();
  const int n = t >> 2, kc = (t & 3) * 16;
#pragma unroll
  for (int i = 0; i < 4; ++i) {
    half4v h;
    h[0] = tile[kc + i * 4 + 0][n];
    h[1] = tile[kc + i * 4 + 1][n];
    h[2] = tile[kc + i * 4 + 2][n];
    h[3] = tile[kc + i * 4 + 3][n];
    *(half4v*)&Wt[(size_t)(n0 + n) * K + k0 + kc + i * 4] = h;
  }
}

// ---------------------------------------------------------------------------
// Fused q/kv/r GEMM v14 (A matrices are b-major). 352 blocks x 512 threads.
//  256x256 tile, 8 waves (2M x 4N), per-wave 128x64, acc[8][4].
//  BK=64, XOR-swizzled staging + fragment reads; v13-verified double-buffer
//  choreography: stage(k+1) -> compute(k) -> ONE barrier per k-step.
//  Staging bytes/MFMA 256->128 B (-50%), ds_reads/MFMA x0.75 vs 128^2.
//  LDS 128 KB (A0@0|B0@32K|A1@64K|B1@96K bytes) -> 1 block/CU, 2 waves/SIMD
//  (same TLP as v13's 2 blocks x 4 waves).
//  Block map: q gb<64: bn=(gb&3)*256, bm=(gb>>2)*256
//             kv gb in [64,320): j=gb-64; bn=(j&7)*256; bm=(j>>3)*256
//             r  gb in [320,352): j=gb-320; bn=(j&3)*256; bm=(j>>2)*256
// ---------------------------------------------------------------------------
__global__ __launch_bounds__(512, 2) void gemm3(
    const _Float16* __restrict__ Aq, const _Float16* __restrict__ Akv,
    const _Float16* __restrict__ Ar, const _Float16* __restrict__ Btq,
    const _Float16* __restrict__ Btkv, const _Float16* __restrict__ Btr,
    const float* __restrict__ bq, const float* __restrict__ bkv,
    const float* __restrict__ br, const float* __restrict__ uu,
    _Float16* __restrict__ qfu, _Float16* __restrict__ kf,
    _Float16* __restrict__ vfT, _Float16* __restrict__ rf) {
  __shared__ _Float16 smem[65536];  // 128 KB
  const int gb = blockIdx.x;
  const _Float16* A;
  const _Float16* Bt;
  const float* bias;
  int mode, bm, bn;
  if (gb < 64) {
    mode = 1; A = Aq; Bt = Btq; bias = bq;
    bn = (gb & 3) * 256; bm = (gb >> 2) * 256;
  } else if (gb < 320) {
    mode = 2; A = Akv; Bt = Btkv; bias = bkv;
    const int j = gb - 64;
    bn = (j & 7) * 256; bm = (j >> 3) * 256;
  } else {
    mode = 3; A = Ar; Bt = Btr; bias = br;
    const int j = gb - 320;
    bn = (j & 3) * 256; bm = (j >> 2) * 256;
  }
  const int K = 1024;
  const int t = threadIdx.x, w = t >> 6, l = t & 63;
  const int l15 = l & 15, l4 = l >> 4;
  const int wm = (w >> 2) * 128, wn = (w & 3) * 64;

  f32x4 acc[8][4];
  const f32x4 z4 = {0.f, 0.f, 0.f, 0.f};
#pragma unroll
  for (int i = 0; i < 8; ++i)
#pragma unroll
    for (int j = 0; j < 4; ++j) acc[i][j] = z4;

  const char* Abase = (const char*)A + (size_t)bm * K * 2;
  const char* Bbase = (const char*)Bt + (size_t)bn * K * 2;

  // ---- prologue: stage k0=0 into buffer 0 ----
#pragma unroll
  for (int iss = 0; iss < 4; ++iss) {
    const int off = (t + iss * 512) * 16;  // 0..32752
    const int row = off >> 7;              // 0..255
    const int sw = ((((off >> 4) & 7) ^ (row & 7)) << 4);
    load_lds16(Abase + (size_t)row * (K * 2) + sw, (char*)smem + off);
    load_lds16(Bbase + (size_t)row * (K * 2) + sw, (char*)smem + 32768 + off);
  }
  __syncthreads();

  int cur = 0;
  for (int k0 = 0; k0 < K; k0 += 64) {
    // ---- issue next-step staging (flies under this step's MFMAs) ----
    if (k0 + 64 < K) {
      const int nb = cur ^ 1;
#pragma unroll
      for (int iss = 0; iss < 4; ++iss) {
        const int off = (t + iss * 512) * 16;
        const int row = off >> 7;
        const int sw = ((((off >> 4) & 7) ^ (row & 7)) << 4);
        load_lds16(Abase + (size_t)row * (K * 2) + (k0 + 64) * 2 + sw,
                   (char*)smem + nb * 65536 + off);
        load_lds16(Bbase + (size_t)row * (K * 2) + (k0 + 64) * 2 + sw,
                   (char*)smem + nb * 65536 + 32768 + off);
      }
    }
    const _Float16* Asc = smem + cur * 32768;
    const _Float16* Bsc = smem + cur * 32768 + 16384;
#pragma unroll
    for (int ks = 0; ks < 2; ++ks) {
      const int ch = ((ks * 4 + l4) ^ (l15 & 7)) * 8;
      half8 af[8], bf[4];
#pragma unroll
      for (int mt = 0; mt < 8; ++mt)
        af[mt] = *(const half8*)&Asc[(wm + mt * 16 + l15) * 64 + ch];
#pragma unroll
      for (int nt = 0; nt < 4; ++nt)
        bf[nt] = *(const half8*)&Bsc[(wn + nt * 16 + l15) * 64 + ch];
#pragma unroll
      for (int mt = 0; mt < 8; ++mt)
#pragma unroll
        for (int nt = 0; nt < 4; ++nt)
          acc[mt][nt] = __builtin_amdgcn_mfma_f32_16x16x32_f16(
              af[mt], bf[nt], acc[mt][nt], 0, 0, 0);
    }
    __syncthreads();  // single per-step drain: stage(k+1) lands AFTER compute
    cur ^= 1;
  }

  if (mode == 2 && bn >= 1024) {
    // ---- V half: LDS transpose -> coalesced vfT[bh][d][j] stores ----
    // 4 chunks of 64 cols; chunk ch2 is owned by the 2 waves with wcol==ch2.
    const int b = bm >> 11, j0m = bm & 2047;
    const int hbase = (bn - 1024) >> 6;  // head of chunk 0
#pragma unroll
    for (int ch2 = 0; ch2 < 4; ++ch2) {
      __syncthreads();
      if ((w & 3) == ch2) {
#pragma unroll
        for (int mt = 0; mt < 8; ++mt)
#pragma unroll
          for (int r = 0; r < 4; ++r) {
            const int rowl = wm + mt * 16 + l4 * 4 + r;  // 0..255
#pragma unroll
            for (int nt = 0; nt < 4; ++nt) {
              const int coll = nt * 16 + l15;  // 0..63
              smem[rowl * 66 + coll] =
                  (_Float16)(acc[mt][nt][r] + bias[bn + ch2 * 64 + coll]);
            }
          }
      }
      __syncthreads();
#pragma unroll
      for (int it = 0; it < 4; ++it) {
        const int c = t + 512 * it;          // 0..2047
        const int d = c >> 5, ck = c & 31;   // d 0..63, ck 0..31 (8 j each)
        half8 v8;
#pragma unroll
        for (int z = 0; z < 8; ++z) v8[z] = smem[(ck * 8 + z) * 66 + d];
        *(half8*)&vfT[(((size_t)(b * 16 + hbase + ch2) * 64 + d) << 11) + j0m +
                      ck * 8] = v8;
      }
    }
    return;
  }

#pragma unroll
  for (int mt = 0; mt < 8; ++mt)
#pragma unroll
    for (int r = 0; r < 4; ++r) {
      const int rowl = wm + mt * 16 + l4 * 4 + r;  // 0..255
#pragma unroll
      for (int nt = 0; nt < 4; ++nt) {
        const int col = bn + wn + nt * 16 + l15;
        const float val = acc[mt][nt][r] + bias[col];
        if (mode == 1) {
          const int b = bm >> 10, i0m = bm & 1023;
          const int h = col >> 6, d = col & 63;
          qfu[(((size_t)(b * 16 + h) * 1024 + i0m + rowl) << 6) + d] =
              (_Float16)((val + uu[col]) * 0.125f);
        } else if (mode == 2) {
          const int b = bm >> 11, j0m = bm & 2047;
          const int h = col >> 6, d = col & 63;
          kf[(((size_t)(b * 16 + h) * 2048 + j0m + rowl) << 6) + d] =
              (_Float16)val;
        } else {
          const int h = col >> 6, d = col & 63;
          rf[(((size_t)h * 2048 + bm + rowl) << 6) + d] = (_Float16)val;
        }
      }
    }
}

// ---------------------------------------------------------------------------
// proj GEMM v13: out f32 [M][N] = A @ Bt^T + bias. 128x64 tiles, 512 blocks;
// double-buffered (48 KB LDS: As0@0 | Bs0@16K | As1@24K | Bs1@40K bytes).
// ---------------------------------------------------------------------------
__global__ __launch_bounds__(256, 2) void gemm_proj(
    const _Float16* __restrict__ A, const _Float16* __restrict__ Bt,
    const float* __restrict__ bias, float* __restrict__ out0, int M, int N,
    int K) {
  __shared__ _Float16 smem[24576];  // 48 KB
  const int t = threadIdx.x, w = t >> 6, l = t & 63;
  const int l15 = l & 15, l4 = l >> 4;
  const int bm = blockIdx.y * 128, bn = blockIdx.x * 64;
  const int wm = (w >> 1) * 64, wn = (w & 1) * 32;

  f32x4 acc[4][2];
  const f32x4 z4 = {0.f, 0.f, 0.f, 0.f};
#pragma unroll
  for (int i = 0; i < 4; ++i)
#pragma unroll
    for (int j = 0; j < 2; ++j) acc[i][j] = z4;

  const char* Abase = (const char*)A + (size_t)bm * K * 2;
  const char* Bbase = (const char*)Bt + (size_t)bn * K * 2;

  // ---- prologue: stage k0=0 into buffer 0 ----
#pragma unroll
  for (int iss = 0; iss < 4; ++iss) {
    const int off = w * 4096 + iss * 1024 + l * 16;
    const int row = off >> 7;
    const int sw = ((((off >> 4) & 7) ^ (row & 7)) << 4);
    load_lds16(Abase + (size_t)row * (K * 2) + sw, (char*)smem + off);
  }
#pragma unroll
  for (int iss = 0; iss < 2; ++iss) {
    const int off = w * 1024 + iss * 4096 + l * 16;
    const int row = off >> 7;
    const int sw = ((((off >> 4) & 7) ^ (row & 7)) << 4);
    load_lds16(Bbase + (size_t)row * (K * 2) + sw, (char*)smem + 16384 + off);
  }
  __syncthreads();

  int cur = 0;
  for (int k0 = 0; k0 < K; k0 += 64) {
    if (k0 + 64 < K) {
      const int nb = cur ^ 1;
#pragma unroll
      for (int iss = 0; iss < 4; ++iss) {
        const int off = w * 4096 + iss * 1024 + l * 16;
        const int row = off >> 7;
        const int sw = ((((off >> 4) & 7) ^ (row & 7)) << 4);
        load_lds16(Abase + (size_t)row * (K * 2) + (k0 + 64) * 2 + sw,
                   (char*)smem + nb * 24576 + off);
      }
#pragma unroll
      for (int iss = 0; iss < 2; ++iss) {
        const int off = w * 1024 + iss * 4096 + l * 16;
        const int row = off >> 7;
        const int sw = ((((off >> 4) & 7) ^ (row & 7)) << 4);
        load_lds16(Bbase + (size_t)row * (K * 2) + (k0 + 64) * 2 + sw,
                   (char*)smem + nb * 24576 + 16384 + off);
      }
    }
    const _Float16* Asc = smem + cur * 12288;
    const _Float16* Bsc = smem + cur * 12288 + 8192;
#pragma unroll
    for (int ks = 0; ks < 2; ++ks) {
      const int ch = ((ks * 4 + l4) ^ (l15 & 7)) * 8;
      half8 af[4], bf[2];
#pragma unroll
      for (int mt = 0; mt < 4; ++mt)
        af[mt] = *(const half8*)&Asc[(wm + mt * 16 + l15) * 64 + ch];
#pragma unroll
      for (int nt = 0; nt < 2; ++nt)
        bf[nt] = *(const half8*)&Bsc[(wn + nt * 16 + l15) * 64 + ch];
#pragma unroll
      for (int mt = 0; mt < 4; ++mt)
#pragma unroll
        for (int nt = 0; nt < 2; ++nt)
          acc[mt][nt] = __builtin_amdgcn_mfma_f32_16x16x32_f16(
              af[mt], bf[nt], acc[mt][nt], 0, 0, 0);
    }
    __syncthreads();
    cur ^= 1;
  }

#pragma unroll
  for (int mt = 0; mt < 4; ++mt)
#pragma unroll
    for (int r = 0; r < 4; ++r) {
      const int row = bm + wm + mt * 16 + l4 * 4 + r;
#pragma unroll
      for (int nt = 0; nt < 2; ++nt) {
        const int col = bn + wn + nt * 16 + l15;
        out0[(size_t)row * N + col] = acc[mt][nt][r] + bias[col];
      }
    }
}

// ---------------------------------------------------------------------------
// MFMA flash attention v9 (verified 101.9 us): 128 q-rows per block
// (2 row-groups per wave), shared ks/vts fragment reads feed both groups.
// ---------------------------------------------------------------------------
__global__ __launch_bounds__(256, 2) void attn_mfma(
    const _Float16* __restrict__ qfu,  // [bh][1024][64]  (q+b+u)*0.125
    const _Float16* __restrict__ kf,   // [bh][2048][64]
    const _Float16* __restrict__ vfT,  // [bh][64][2048]
    const _Float16* __restrict__ rf,   // [h][2048][64]
    const float* __restrict__ u,       // [16][64]
    const float* __restrict__ v,       // [16][64]
    _Float16* __restrict__ attn_out)   // [i*4+b][1024] f16
{
  __shared__ _Float16 ks[64 * 64];        // [j][d] swizzled
  __shared__ _Float16 vts[64 * 64];       // [d][j] swizzled
  __shared__ _Float16 rs[256 * 64];       // ring (slot = m & 255), swizzled
  __shared__ _Float16 pA[2][4][16 * 64];  // per-group, per-wave probs

  const int t = threadIdx.x, w = t >> 6, l = t & 63;
  const int l15 = l & 15, l4 = l >> 4;
  const int id = blockIdx.x;
  // XCD swizzle on id&63; qt in [0,8): first 256 ids heavy (bx 7..4),
  // second 256 light (bx 0..3) so (id, id+256) pairs sum njt = 50.
  const int bh = ((id >> 3) & 7) * 8 + (id & 7);
  const int qt = id >> 6;
  const int bx = (qt < 4) ? (7 - qt) : (qt - 4);
  const int i0 = bx * 128;
  const int h = bh & 15, b = bh >> 4;

  const char* kfb = (const char*)(kf + (((size_t)bh * 2048) << 6));
  const char* vg = (const char*)(vfT + (((size_t)bh) << 17));
  const char* rg = (const char*)(rf + (((size_t)h) << 17));

  // q fragments for both groups; qv = qa + (v-u)*0.125 in-register
  half8 qa0[2], qa1[2], qv0[2], qv1[2];
  {
    half8 dl0, dl1;
#pragma unroll
    for (int z = 0; z < 8; ++z) {
      const int di = l4 * 8 + z;
      dl0[z] = (_Float16)(0.125f * (v[h * 64 + di] - u[h * 64 + di]));
      dl1[z] = (_Float16)(0.125f * (v[h * 64 + 32 + di] - u[h * 64 + 32 + di]));
    }
#pragma unroll
    for (int g = 0; g < 2; ++g) {
      const size_t qo =
          (((size_t)bh * 1024 + i0 + 64 * g + w * 16 + l15) << 6) + l4 * 8;
      qa0[g] = *(const half8*)(qfu + qo);
      qa1[g] = *(const half8*)(qfu + qo + 32);
      qv0[g] = qa0[g] + dl0;
      qv1[g] = qa1[g] + dl1;
    }
  }
  const f32x4 z4 = {0.f, 0.f, 0.f, 0.f};
  f32x4 o[2][4];
  float lsum[2][4];
#pragma unroll
  for (int g = 0; g < 2; ++g)
#pragma unroll
    for (int nt = 0; nt < 4; ++nt) { o[g][nt] = z4; lsum[g][nt] = 0.f; }

  const int mb0 = 960 - i0;  // group0 m_base at jt=0 (>= 64; mb0-64 >= 0)
  const int njt = 2 * bx + 18;

  // ---- prologue: stage initial 192-row r window [mb0-64, mb0+128) ----
#pragma unroll
  for (int iss = 0; iss < 6; ++iss) {
    const int off = w * 1024 + iss * 4096 + l * 16;
    const int q = off >> 7;  // 0..191
    const int cph = (off >> 4) & 7;
    const int slot = (mb0 - 64 + q) & 255;
    int m = mb0 - 64 + q;
    m = m < 2047 ? m : 2047;
    load_lds16(rg + (size_t)m * 128 + ((cph ^ (slot & 7)) << 4),
               (char*)rs + slot * 128 + cph * 16);
  }

  for (int jt = 0; jt < njt; ++jt) {
    const int j0 = jt * 64;
    const int m_base = j0 - i0 + 960;  // group0 base
    __syncthreads();  // prior tile's reads done before overwrite
    // ---- stage K, V^T (swizzled source) ----
    {
      const char* kg = kfb + (size_t)j0 * 128;
#pragma unroll
      for (int iss = 0; iss < 2; ++iss) {
        const int off = w * 1024 + iss * 4096 + l * 16;
        const int row = off >> 7;
        const int cph = (off >> 4) & 7;
        const int sw = ((cph ^ (row & 7)) << 4);
        load_lds16(kg + (size_t)row * 128 + sw, (char*)ks + off);
        load_lds16(vg + (size_t)row * 4096 + (size_t)j0 * 2 + sw,
                   (char*)vts + off);
      }
    }
    // ---- stage 64 new r rows [m_base+64, m_base+128) into ring ----
    if (jt > 0) {
      const int m0 = m_base + 64;
#pragma unroll
      for (int iss = 0; iss < 2; ++iss) {
        const int off = w * 1024 + iss * 4096 + l * 16;
        const int q = off >> 7;  // 0..63
        const int cph = (off >> 4) & 7;
        const int slot = (m0 + q) & 255;
        int m = m0 + q;
        m = m < 2047 ? m : 2047;
        load_lds16(rg + (size_t)m * 128 + ((cph ^ (slot & 7)) << 4),
                   (char*)rs + slot * 128 + cph * 16);
      }
    }
    __syncthreads();

    // ---- content scores: shared ks reads feed both groups ----
    f32x4 sc[2][4];
#pragma unroll
    for (int nt = 0; nt < 4; ++nt) {
      const int row = nt * 16 + l15;
      const int rsw = row & 7;
      const half8 b0 = *(const half8*)&ks[row * 64 + ((l4 ^ rsw) * 8)];
      const half8 b1 = *(const half8*)&ks[row * 64 + (((4 + l4) ^ rsw) * 8)];
#pragma unroll
      for (int g = 0; g < 2; ++g) {
        f32x4 cc = z4;
        cc = __builtin_amdgcn_mfma_f32_16x16x32_f16(qa0[g], b0, cc, 0, 0, 0);
        cc = __builtin_amdgcn_mfma_f32_16x16x32_f16(qa1[g], b1, cc, 0, 0, 0);
        sc[g][nt] = cc;
      }
    }

    // ---- per group: position scores + softmax ----
#pragma unroll
    for (int g = 0; g < 2; ++g) {
      const int cw = i0 + 64 * g - j0 + 1024 + 16 * w;
      if (g == 0 && cw < -15) continue;  // group0 fully masked (tail tile)
      const int mbg = m_base - 64 * g;
      f32x4 accP[5];
#pragma unroll
      for (int p = 0; p < 5; ++p) {
        const int m = mbg + (3 - w + p) * 16 + l15;
        const int slot = m & 255;
        const int ssw = slot & 7;
        const half8 b0 = *(const half8*)&rs[slot * 64 + ((l4 ^ ssw) * 8)];
        const half8 b1 = *(const half8*)&rs[slot * 64 + (((4 + l4) ^ ssw) * 8)];
        f32x4 cc = z4;
        cc = __builtin_amdgcn_mfma_f32_16x16x32_f16(qv0[g], b0, cc, 0, 0, 0);
        cc = __builtin_amdgcn_mfma_f32_16x16x32_f16(qv1[g], b1, cc, 0, 0, 0);
        accP[p] = cc;
      }
      if (cw >= 63) {  // wave-uniform: no masking possible in this tile
#pragma unroll
        for (int r = 0; r < 4; ++r) {
          const int thr = 4 * l4 + r;
          const int srcl = (l4 << 4) | ((15 + l15 - thr) & 15);
          float rot[5];
#pragma unroll
          for (int p = 0; p < 5; ++p) rot[p] = __shfl(accP[p][r], srcl, 64);
          float esum = 0.f;
          const int sw2 = (thr & 7) * 8;
#pragma unroll
          for (int nt = 0; nt < 4; ++nt) {
            const float pv = (l15 <= thr) ? rot[nt] : rot[nt + 1];
            const float e = __expf(sc[g][nt][r] + pv);
            esum += e;
            pA[g][w][thr * 64 + ((16 * nt + l15) ^ sw2)] = (_Float16)e;
          }
          lsum[g][r] += esum;
        }
      } else {
#pragma unroll
        for (int r = 0; r < 4; ++r) {
          const int thr = 4 * l4 + r;
          const int srcl = (l4 << 4) | ((15 + l15 - thr) & 15);
          float rot[5];
#pragma unroll
          for (int p = 0; p < 5; ++p) rot[p] = __shfl(accP[p][r], srcl, 64);
          float esum = 0.f;
          const int sw2 = (thr & 7) * 8;
#pragma unroll
          for (int nt = 0; nt < 4; ++nt) {
            const float pv = (l15 <= thr) ? rot[nt] : rot[nt + 1];
            const bool masked = (16 * nt + l15) > (cw + thr);
            const float e = masked ? 0.f : __expf(sc[g][nt][r] + pv);
            esum += e;
            pA[g][w][thr * 64 + ((16 * nt + l15) ^ sw2)] = (_Float16)e;
          }
          lsum[g][r] += esum;
        }
      }
    }

    // ---- PV: shared vts reads feed both groups ----
    const bool act0 = (i0 - j0 + 1024 + 16 * w) >= -15;
#pragma unroll
    for (int kk = 0; kk < 2; ++kk) {
      const int aoff = l15 * 64 + ((kk * 32 + l4 * 8) ^ ((l15 & 7) * 8));
      half8 a81 = *(const half8*)&pA[1][w][aoff];
      half8 a80;
      if (act0) a80 = *(const half8*)&pA[0][w][aoff];
#pragma unroll
      for (int nt = 0; nt < 4; ++nt) {
        const int row = nt * 16 + l15;
        const half8 b8 =
            *(const half8*)&vts[row * 64 + ((((kk << 2) + l4) ^ (row & 7)) * 8)];
        if (act0)
          o[0][nt] =
              __builtin_amdgcn_mfma_f32_16x16x32_f16(a80, b8, o[0][nt], 0, 0, 0);
        o[1][nt] =
            __builtin_amdgcn_mfma_f32_16x16x32_f16(a81, b8, o[1][nt], 0, 0, 0);
      }
    }
  }

  // ---- epilogue ----
#pragma unroll
  for (int g = 0; g < 2; ++g)
#pragma unroll
    for (int r = 0; r < 4; ++r) {
      float s = lsum[g][r];
      s += __shfl_xor(s, 1, 64);
      s += __shfl_xor(s, 2, 64);
      s += __shfl_xor(s, 4, 64);
      s += __shfl_xor(s, 8, 64);
      const float inv = 1.0f / s;
      const int i = i0 + 64 * g + w * 16 + l4 * 4 + r;
      const size_t base = ((size_t)i * 4 + b) * 1024 + h * 64;
#pragma unroll
      for (int nt = 0; nt < 4; ++nt)
        attn_out[base + nt * 16 + l15] = (_Float16)(o[g][nt][r] * inv);
    }
}

// ---------------------------------------------------------------------------
extern "C" void kernel_launch(void* const* d_in, const int* in_sizes, int n_in,
                              void* d_out, int out_size, void* d_ws,
                              size_t ws_size, hipStream_t stream) {
  const float* inputs   = (const float*)d_in[0];
  const float* pos_emb  = (const float*)d_in[1];
  const float* full_inp = (const float*)d_in[2];
  const float* u        = (const float*)d_in[3];
  const float* v        = (const float*)d_in[4];
  const float* W_kv   = (const float*)d_in[6];
  const float* b_kv   = (const float*)d_in[7];
  const float* W_q    = (const float*)d_in[8];
  const float* b_q    = (const float*)d_in[9];
  const float* W_pos  = (const float*)d_in[10];
  const float* b_pos  = (const float*)d_in[11];
  const float* W_proj = (const float*)d_in[12];
  const float* b_proj = (const float*)d_in[13];
  float* out = (float*)d_out;

  char* ws = (char*)d_ws;
  const size_t MB = 1024 * 1024;
  _Float16* in_q_h    = (_Float16*)(ws);            // 8 MB  (b-major 4096x1024)
  _Float16* in_full_h = (_Float16*)(ws + 8 * MB);   // 16 MB (b-major 8192x1024)
  _Float16* in_pos_h  = (_Float16*)(ws + 24 * MB);  // 4 MB  (2048x1024)
  _Float16* attn_h    = (_Float16*)(ws + 28 * MB);  // 8 MB  (4096x1024)
  _Float16* wq_t      = (_Float16*)(ws + 36 * MB);  // 2 MB
  _Float16* wkv_t     = (_Float16*)(ws + 38 * MB);  // 4 MB
  _Float16* wpos_t    = (_Float16*)(ws + 42 * MB);  // 2 MB
  _Float16* wproj_t   = (_Float16*)(ws + 44 * MB);  // 2 MB
  _Float16* qfu       = (_Float16*)(ws + 46 * MB);  // 8 MB  [bh][1024][64]
  _Float16* kf        = (_Float16*)(ws + 54 * MB);  // 16 MB [bh][2048][64]
  _Float16* vfT       = (_Float16*)(ws + 70 * MB);  // 16 MB [bh][64][2048]
  _Float16* rf        = (_Float16*)(ws + 86 * MB);  // 4 MB  [h][2048][64]

  const dim3 blk(256);
  prep<<<dim3(3328), blk, 0, stream>>>(inputs, full_inp, pos_emb, W_q, W_kv,
                                       W_pos, W_proj, in_q_h, in_full_h,
                                       in_pos_h, wq_t, wkv_t, wpos_t, wproj_t);
  gemm3<<<dim3(352), dim3(512), 0, stream>>>(in_q_h, in_full_h, in_pos_h, wq_t,
                                             wkv_t, wpos_t, b_q, b_kv, b_pos,
                                             u, qfu, kf, vfT, rf);
  attn_mfma<<<dim3(512), blk, 0, stream>>>(qfu, kf, vfT, rf, u, v, attn_h);
  gemm_proj<<<dim3(16, 32), blk, 0, stream>>>(attn_h, wproj_t, b_proj, out,
                                              4096, 1024, 1024);
}